// Round 19
// baseline (475.228 us; speedup 1.0000x reference)
//
#include <hip/hip_runtime.h>

#define TT 64
#define NN 512
#define DD 128

typedef __attribute__((ext_vector_type(8))) short bf16x8;
typedef __attribute__((ext_vector_type(4))) float f32x4;

__device__ __forceinline__ unsigned cvtpk(float lo, float hi) {
  unsigned r;
  asm("v_cvt_pk_bf16_f32 %0, %1, %2" : "=v"(r) : "v"(lo), "v"(hi));
  return r;
}

__device__ __forceinline__ float bf2f(unsigned short v) {
  return __uint_as_float((unsigned)v << 16);
}

// XOR-swizzled LDS index helpers (units: unsigned short elements).
__device__ __forceinline__ int swz128(int row, int col) {
  return row * 128 + (((col >> 3) ^ (row & 15)) << 3) + (col & 7);
}
__device__ __forceinline__ int swz64(int row, int col) {
  return row * 64 + (((col >> 3) ^ (row & 7)) << 3) + (col & 7);
}

// Barrier with LDS-only drain: global loads stay in flight across it.
__device__ __forceinline__ void bar() {
  asm volatile("s_waitcnt lgkmcnt(0)" ::: "memory");
  __builtin_amdgcn_s_barrier();
  asm volatile("" ::: "memory");
}

// 16-lane (DPP-row) sum via row_ror butterflies — VALU pipe, no LDS traffic.
__device__ __forceinline__ float red16(float s) {
  int t;
  t = __builtin_amdgcn_update_dpp(0, __float_as_int(s), 0x121, 0xf, 0xf, false);
  s += __int_as_float(t);
  t = __builtin_amdgcn_update_dpp(0, __float_as_int(s), 0x122, 0xf, 0xf, false);
  s += __int_as_float(t);
  t = __builtin_amdgcn_update_dpp(0, __float_as_int(s), 0x124, 0xf, 0xf, false);
  s += __int_as_float(t);
  t = __builtin_amdgcn_update_dpp(0, __float_as_int(s), 0x128, 0xf, 0xf, false);
  s += __int_as_float(t);
  return s;
}

// transpose fp32 [K][N] -> bf16 [N][K]
__global__ void wprep(const float* __restrict__ src, unsigned short* __restrict__ dst,
                      int K, int Nn) {
  int idx = blockIdx.x * 256 + threadIdx.x;
  if (idx >= K * Nn) return;
  int n = idx / K, k = idx - n * K;
  float f = src[k * Nn + n];
  unsigned u = __float_as_uint(f);
  u += 0x7fffu + ((u >> 16) & 1u);
  dst[idx] = (unsigned short)(u >> 16);
}

#define KSCL 0.36067376022224085f   // 0.25 * log2(e), folded into K epilogue

// ============================ KERNEL A =====================================
// LN1 + col-strip QKV + wave-local causal attention -> AO (bf16) to global.
__global__ __launch_bounds__(512, 4)
void attn_head(const float* __restrict__ x_in, const float* __restrict__ ste,
               const float* __restrict__ g1, const float* __restrict__ b1,
               const unsigned short* __restrict__ wqt, const float* __restrict__ bq,
               const unsigned short* __restrict__ wkt, const float* __restrict__ bk,
               const unsigned short* __restrict__ wvt, const float* __restrict__ bv,
               unsigned short* __restrict__ aoG) {
  __shared__ __align__(16) unsigned short smem[32768];  // 64 KB

  const int tid = threadIdx.x;
  const int lane = tid & 63;
  const int w  = tid >> 6;         // wave 0..7
  const int lg = lane >> 4;        // 0..3
  const int li = lane & 15;
  const int hc = w * 16;           // col-strip base == head base

  const int blk = blockIdx.x;
  const int b = blk >> 9;          // N=512
  const int n = blk & 511;
  const int rs = NN * DD;
  const float* xbase = x_in + (b * TT * NN + n) * DD;
  const float* sbase = ste + (b * TT * NN + n) * DD;

  unsigned short* X2s = smem;
  unsigned short* Qb  = smem;
  unsigned short* AOb = smem + 8192;
  unsigned short* Kb  = smem + 16384;
  unsigned short* Vt  = smem + 24576;

  #define SWZ256(row, col) ((row) * 256 + ((((col) >> 3) ^ ((row) & 15)) << 3) + ((col) & 7))

  // ---------------- LN1 + STE -> X2 (all input loads hoisted) --------------
  {
    const int t0 = w * 8 + lg;
    const float* xr0 = xbase + t0 * rs + li * 8;
    const float* xr1 = xbase + (t0 + 4) * rs + li * 8;
    const float* sr0 = sbase + t0 * rs + li * 8;
    const float* sr1 = sbase + (t0 + 4) * rs + li * 8;
    float4 xA0 = *(const float4*)(xr0);
    float4 xB0 = *(const float4*)(xr0 + 4);
    float4 xA1 = *(const float4*)(xr1);
    float4 xB1 = *(const float4*)(xr1 + 4);
    float4 sA0 = *(const float4*)(sr0);
    float4 sB0 = *(const float4*)(sr0 + 4);
    float4 sA1 = *(const float4*)(sr1);
    float4 sB1 = *(const float4*)(sr1 + 4);
    float4 gA = *(const float4*)(g1 + li * 8);
    float4 gB = *(const float4*)(g1 + li * 8 + 4);
    float4 bA = *(const float4*)(b1 + li * 8);
    float4 bB = *(const float4*)(b1 + li * 8 + 4);

    {  // row t0
      float s1 = xA0.x + xA0.y + xA0.z + xA0.w + xB0.x + xB0.y + xB0.z + xB0.w;
      float s2 = xA0.x * xA0.x + xA0.y * xA0.y + xA0.z * xA0.z + xA0.w * xA0.w +
                 xB0.x * xB0.x + xB0.y * xB0.y + xB0.z * xB0.z + xB0.w * xB0.w;
      s1 = red16(s1); s2 = red16(s2);
      float mean = s1 * (1.0f / 128.0f);
      float var = fmaxf((s2 - s1 * mean) * (1.0f / 127.0f), 0.0f);  // ddof=1
      float inv = 1.0f / (sqrtf(var) + 1e-6f);
      unsigned o01 = cvtpk(gA.x * (xA0.x - mean) * inv + bA.x, gA.y * (xA0.y - mean) * inv + bA.y);
      unsigned o23 = cvtpk(gA.z * (xA0.z - mean) * inv + bA.z, gA.w * (xA0.w - mean) * inv + bA.w);
      unsigned o45 = cvtpk(gB.x * (xB0.x - mean) * inv + bB.x, gB.y * (xB0.y - mean) * inv + bB.y);
      unsigned o67 = cvtpk(gB.z * (xB0.z - mean) * inv + bB.z, gB.w * (xB0.w - mean) * inv + bB.w);
      *(uint4*)(X2s + SWZ256(t0, li * 8)) = (uint4){o01, o23, o45, o67};
    }
    {  // row t0+4
      float s1 = xA1.x + xA1.y + xA1.z + xA1.w + xB1.x + xB1.y + xB1.z + xB1.w;
      float s2 = xA1.x * xA1.x + xA1.y * xA1.y + xA1.z * xA1.z + xA1.w * xA1.w +
                 xB1.x * xB1.x + xB1.y * xB1.y + xB1.z * xB1.z + xB1.w * xB1.w;
      s1 = red16(s1); s2 = red16(s2);
      float mean = s1 * (1.0f / 128.0f);
      float var = fmaxf((s2 - s1 * mean) * (1.0f / 127.0f), 0.0f);
      float inv = 1.0f / (sqrtf(var) + 1e-6f);
      unsigned o01 = cvtpk(gA.x * (xA1.x - mean) * inv + bA.x, gA.y * (xA1.y - mean) * inv + bA.y);
      unsigned o23 = cvtpk(gA.z * (xA1.z - mean) * inv + bA.z, gA.w * (xA1.w - mean) * inv + bA.w);
      unsigned o45 = cvtpk(gB.x * (xB1.x - mean) * inv + bB.x, gB.y * (xB1.y - mean) * inv + bB.y);
      unsigned o67 = cvtpk(gB.z * (xB1.z - mean) * inv + bB.z, gB.w * (xB1.w - mean) * inv + bB.w);
      *(uint4*)(X2s + SWZ256(t0 + 4, li * 8)) = (uint4){o01, o23, o45, o67};
    }
    *(uint4*)(X2s + SWZ256(t0, 128 + li * 8)) =
        (uint4){cvtpk(sA0.x, sA0.y), cvtpk(sA0.z, sA0.w), cvtpk(sB0.x, sB0.y), cvtpk(sB0.z, sB0.w)};
    *(uint4*)(X2s + SWZ256(t0 + 4, 128 + li * 8)) =
        (uint4){cvtpk(sA1.x, sA1.y), cvtpk(sA1.z, sA1.w), cvtpk(sB1.x, sB1.y), cvtpk(sB1.z, sB1.w)};
  }

  bar();  // B0: X2 visible

  // ---------------- V-pass (cols hc..hc+15), immediate epi -> Vt -----------
  {
    const unsigned short* vB = wvt + hc * 256;
    f32x4 va[4];
    #pragma unroll
    for (int rg = 0; rg < 4; ++rg) va[rg] = (f32x4){0, 0, 0, 0};
    #pragma unroll
    for (int kk = 0; kk < 8; ++kk) {
      bf16x8 bc = *(const bf16x8*)(vB + li * 256 + kk * 32 + lg * 8);
      #pragma unroll
      for (int rg = 0; rg < 4; ++rg) {
        bf16x8 af = *(const bf16x8*)(X2s + SWZ256(rg * 16 + li, kk * 32 + lg * 8));
        va[rg] = __builtin_amdgcn_mfma_f32_16x16x32_bf16(af, bc, va[rg], 0, 0, 0);
      }
    }
    float bvv = bv[hc + li];
    int d = hc + li;
    #pragma unroll
    for (int rg = 0; rg < 4; ++rg) {
      float v0 = fmaxf(va[rg][0] + bvv, 0.0f);
      float v1 = fmaxf(va[rg][1] + bvv, 0.0f);
      float v2 = fmaxf(va[rg][2] + bvv, 0.0f);
      float v3 = fmaxf(va[rg][3] + bvv, 0.0f);
      uint2 pv; pv.x = cvtpk(v0, v1); pv.y = cvtpk(v2, v3);
      *(uint2*)(Vt + swz64(d, rg * 16 + lg * 4)) = pv;
    }
  }

  // ---------------- K-pass (cols hc..hc+15), immediate epi -> Kb -----------
  {
    const unsigned short* kB = wkt + hc * 256;
    f32x4 ka[4];
    #pragma unroll
    for (int rg = 0; rg < 4; ++rg) ka[rg] = (f32x4){0, 0, 0, 0};
    #pragma unroll
    for (int kk = 0; kk < 8; ++kk) {
      bf16x8 bc = *(const bf16x8*)(kB + li * 256 + kk * 32 + lg * 8);
      #pragma unroll
      for (int rg = 0; rg < 4; ++rg) {
        bf16x8 af = *(const bf16x8*)(X2s + SWZ256(rg * 16 + li, kk * 32 + lg * 8));
        ka[rg] = __builtin_amdgcn_mfma_f32_16x16x32_bf16(af, bc, ka[rg], 0, 0, 0);
      }
    }
    float bkv = bk[hc + li];
    int col = hc + li;
    #pragma unroll
    for (int rg = 0; rg < 4; ++rg) {
      float k0 = fmaxf(ka[rg][0] + bkv, 0.0f) * KSCL;
      float k1 = fmaxf(ka[rg][1] + bkv, 0.0f) * KSCL;
      float k2 = fmaxf(ka[rg][2] + bkv, 0.0f) * KSCL;
      float k3 = fmaxf(ka[rg][3] + bkv, 0.0f) * KSCL;
      unsigned p01 = cvtpk(k0, k1), p23 = cvtpk(k2, k3);
      Kb[swz128(rg * 16 + lg * 4 + 0, col)] = (unsigned short)p01;
      Kb[swz128(rg * 16 + lg * 4 + 1, col)] = (unsigned short)(p01 >> 16);
      Kb[swz128(rg * 16 + lg * 4 + 2, col)] = (unsigned short)p23;
      Kb[swz128(rg * 16 + lg * 4 + 3, col)] = (unsigned short)(p23 >> 16);
    }
  }

  // ---------------- Q-pass (cols hc..hc+15) --------------------------------
  f32x4 qa[4];
  #pragma unroll
  for (int rg = 0; rg < 4; ++rg) qa[rg] = (f32x4){0, 0, 0, 0};
  {
    const unsigned short* qB = wqt + hc * 256;
    #pragma unroll
    for (int kk = 0; kk < 8; ++kk) {
      bf16x8 bc = *(const bf16x8*)(qB + li * 256 + kk * 32 + lg * 8);
      #pragma unroll
      for (int rg = 0; rg < 4; ++rg) {
        bf16x8 af = *(const bf16x8*)(X2s + SWZ256(rg * 16 + li, kk * 32 + lg * 8));
        qa[rg] = __builtin_amdgcn_mfma_f32_16x16x32_bf16(af, bc, qa[rg], 0, 0, 0);
      }
    }
  }

  bar();  // B0e: ALL X2 reads done -> Qb/AOb overlays live

  // Q epilogue -> Qb (own col strip; consumed only by this wave)
  {
    float bqv = bq[hc + li];
    int col = hc + li;
    #pragma unroll
    for (int rg = 0; rg < 4; ++rg) {
      float v0 = fmaxf(qa[rg][0] + bqv, 0.0f);
      float v1 = fmaxf(qa[rg][1] + bqv, 0.0f);
      float v2 = fmaxf(qa[rg][2] + bqv, 0.0f);
      float v3 = fmaxf(qa[rg][3] + bqv, 0.0f);
      unsigned p01 = cvtpk(v0, v1), p23 = cvtpk(v2, v3);
      Qb[swz128(rg * 16 + lg * 4 + 0, col)] = (unsigned short)p01;
      Qb[swz128(rg * 16 + lg * 4 + 1, col)] = (unsigned short)(p01 >> 16);
      Qb[swz128(rg * 16 + lg * 4 + 2, col)] = (unsigned short)p23;
      Qb[swz128(rg * 16 + lg * 4 + 3, col)] = (unsigned short)(p23 >> 16);
    }
  }

  // ---------------- causal attention, head w (all strips wave-local) -------
  {
    const bf16x8 zf = (bf16x8){0, 0, 0, 0, 0, 0, 0, 0};
    bf16x8 kf[4], vf[2];
    #pragma unroll
    for (int pt = 0; pt < 4; ++pt)
      kf[pt] = (lg < 2) ? *(const bf16x8*)(Kb + swz128(pt * 16 + li, hc + lg * 8)) : zf;
    #pragma unroll
    for (int ks = 0; ks < 2; ++ks)
      vf[ks] = *(const bf16x8*)(Vt + swz64(hc + li, ks * 32 + lg * 8));

    #pragma unroll
    for (int qt = 0; qt < 4; ++qt) {
      bf16x8 qf = (lg < 2) ? *(const bf16x8*)(Qb + swz128(qt * 16 + li, hc + lg * 8)) : zf;
      f32x4 st[4];
      #pragma unroll
      for (int pt = 0; pt < 4; ++pt)
        if (pt <= qt)
          st[pt] = __builtin_amdgcn_mfma_f32_16x16x32_bf16(kf[pt], qf, (f32x4){0, 0, 0, 0}, 0, 0, 0);

      float ssum = 0.0f;
      unsigned pa[4], pb[4];
      #pragma unroll
      for (int pt = 0; pt < 4; ++pt) {
        if (pt > qt) { pa[pt] = 0; pb[pt] = 0; continue; }
        float e0 = exp2f(st[pt][0]);
        float e1 = exp2f(st[pt][1]);
        float e2 = exp2f(st[pt][2]);
        float e3 = exp2f(st[pt][3]);
        if (pt == qt) {  // diagonal tile: mask p_local > q_local
          e0 = (4 * lg + 0 > li) ? 0.0f : e0;
          e1 = (4 * lg + 1 > li) ? 0.0f : e1;
          e2 = (4 * lg + 2 > li) ? 0.0f : e2;
          e3 = (4 * lg + 3 > li) ? 0.0f : e3;
        }
        ssum += e0 + e1 + e2 + e3;
        pa[pt] = cvtpk(e0, e1);
        pb[pt] = cvtpk(e2, e3);
      }
      ssum += __shfl_xor(ssum, 16, 64);
      ssum += __shfl_xor(ssum, 32, 64);
      float rinv = 1.0f / ssum;

      f32x4 oa = (f32x4){0, 0, 0, 0};
      #pragma unroll
      for (int ks = 0; ks < 2; ++ks) {
        if (ks * 2 > qt) continue;
        unsigned x = pa[2 * ks], y = pa[2 * ks + 1];
        asm("v_permlane32_swap_b32 %0, %1" : "+v"(x), "+v"(y));
        asm("v_permlane16_swap_b32 %0, %1" : "+v"(x), "+v"(y));
        unsigned u2 = pb[2 * ks], v2 = pb[2 * ks + 1];
        asm("v_permlane32_swap_b32 %0, %1" : "+v"(u2), "+v"(v2));
        asm("v_permlane16_swap_b32 %0, %1" : "+v"(u2), "+v"(v2));
        union { unsigned uw[4]; bf16x8 h; } pu;
        pu.uw[0] = x; pu.uw[1] = u2; pu.uw[2] = y; pu.uw[3] = v2;
        oa = __builtin_amdgcn_mfma_f32_16x16x32_bf16(vf[ks], pu.h, oa, 0, 0, 0);
      }
      uint2 ov;
      ov.x = cvtpk(oa[0] * rinv, oa[1] * rinv);
      ov.y = cvtpk(oa[2] * rinv, oa[3] * rinv);
      *(uint2*)(AOb + swz128(qt * 16 + li, hc + lg * 4)) = ov;
    }
  }

  bar();  // B2: AO strips visible

  // Coalesced AO store: wave w -> rows w*8..w*8+7, 16 lanes x 16B per row
  #pragma unroll
  for (int pass = 0; pass < 2; ++pass) {
    int t = w * 8 + pass * 4 + lg;
    uint4 v = *(const uint4*)(AOb + swz128(t, li * 8));
    *(uint4*)(aoG + ((b * TT + t) * NN + n) * DD + li * 8) = v;
  }
  #undef SWZ256
}

// ============================ KERNEL B1: O1+O2+residual ====================
// TWO 16-row tiles per wave, stage-interleaved: tile1's MFMAs hide tile0's
// LDS round-trips and weight-load latency (occupancy is capped at ~2-3
// waves/SIMD by the ~124-reg live set; ILP substitutes for waves).
__global__ __launch_bounds__(64)
void tail_a(unsigned short* __restrict__ aoG, const float* __restrict__ x_in,
            const unsigned short* __restrict__ wo1t, const float* __restrict__ bo1,
            const unsigned short* __restrict__ wo2t, const float* __restrict__ bo2) {
  __shared__ __align__(16) unsigned short smem[8192];  // 16 KB: 2x(Sp+Sp2)
  const int lane = threadIdx.x & 63;
  const int lg = lane >> 4;
  const int li = lane & 15;
  const int R0 = blockIdx.x * 32;

  // O1 both tiles
  bf16x8 afT[2][4];
  #pragma unroll
  for (int t = 0; t < 2; ++t)
    #pragma unroll
    for (int kk = 0; kk < 4; ++kk)
      afT[t][kk] = *(const bf16x8*)(aoG + (R0 + t * 16 + li) * DD + kk * 32 + lg * 8);
  #pragma unroll
  for (int t = 0; t < 2; ++t) {
    unsigned short* Sp = smem + t * 4096;
    #pragma unroll
    for (int h = 0; h < 2; ++h) {
      f32x4 acc[4];
      #pragma unroll
      for (int i = 0; i < 4; ++i) acc[i] = (f32x4){0, 0, 0, 0};
      #pragma unroll
      for (int kk = 0; kk < 4; ++kk)
        #pragma unroll
        for (int ct = 0; ct < 4; ++ct)
          acc[ct] = __builtin_amdgcn_mfma_f32_16x16x32_bf16(
              afT[t][kk],
              *(const bf16x8*)(wo1t + (h * 64 + ct * 16 + li) * 128 + kk * 32 + lg * 8),
              acc[ct], 0, 0, 0);
      #pragma unroll
      for (int ct = 0; ct < 4; ++ct) {
        int col = h * 64 + ct * 16 + li;
        float bv = bo1[col];
        unsigned p01 = cvtpk(fmaxf(acc[ct][0] + bv, 0.0f), fmaxf(acc[ct][1] + bv, 0.0f));
        unsigned p23 = cvtpk(fmaxf(acc[ct][2] + bv, 0.0f), fmaxf(acc[ct][3] + bv, 0.0f));
        Sp[swz128(lg * 4 + 0, col)] = (unsigned short)p01;
        Sp[swz128(lg * 4 + 1, col)] = (unsigned short)(p01 >> 16);
        Sp[swz128(lg * 4 + 2, col)] = (unsigned short)p23;
        Sp[swz128(lg * 4 + 3, col)] = (unsigned short)(p23 >> 16);
      }
    }
  }

  // O2 + residual -> Sp2 (x2 bf16), both tiles
  #pragma unroll
  for (int t = 0; t < 2; ++t) {
    unsigned short* Sp  = smem + t * 4096;
    unsigned short* Sp2 = smem + t * 4096 + 2048;
    const int R = R0 + t * 16;
    bf16x8 af4[4];
    #pragma unroll
    for (int kk = 0; kk < 4; ++kk)
      af4[kk] = *(const bf16x8*)(Sp + swz128(li, kk * 32 + lg * 8));
    #pragma unroll
    for (int h = 0; h < 2; ++h) {
      float xrh[4][4];
      #pragma unroll
      for (int ct = 0; ct < 4; ++ct)
        #pragma unroll
        for (int r = 0; r < 4; ++r)
          xrh[ct][r] = x_in[(R + lg * 4 + r) * DD + h * 64 + ct * 16 + li];
      f32x4 acc[4];
      #pragma unroll
      for (int i = 0; i < 4; ++i) acc[i] = (f32x4){0, 0, 0, 0};
      #pragma unroll
      for (int kk = 0; kk < 4; ++kk)
        #pragma unroll
        for (int ct = 0; ct < 4; ++ct)
          acc[ct] = __builtin_amdgcn_mfma_f32_16x16x32_bf16(
              af4[kk],
              *(const bf16x8*)(wo2t + (h * 64 + ct * 16 + li) * 128 + kk * 32 + lg * 8),
              acc[ct], 0, 0, 0);
      #pragma unroll
      for (int ct = 0; ct < 4; ++ct) {
        int col = h * 64 + ct * 16 + li;
        float bv = bo2[col];
        unsigned p01 = cvtpk(acc[ct][0] + bv + xrh[ct][0], acc[ct][1] + bv + xrh[ct][1]);
        unsigned p23 = cvtpk(acc[ct][2] + bv + xrh[ct][2], acc[ct][3] + bv + xrh[ct][3]);
        Sp2[swz128(lg * 4 + 0, col)] = (unsigned short)p01;
        Sp2[swz128(lg * 4 + 1, col)] = (unsigned short)(p01 >> 16);
        Sp2[swz128(lg * 4 + 2, col)] = (unsigned short)p23;
        Sp2[swz128(lg * 4 + 3, col)] = (unsigned short)(p23 >> 16);
      }
    }
  }

  // x2 -> aoG (in-place, coalesced uint4 rows), both tiles
  #pragma unroll
  for (int t = 0; t < 2; ++t) {
    unsigned short* Sp2 = smem + t * 4096 + 2048;
    #pragma unroll
    for (int p = 0; p < 4; ++p) {
      int r = p * 4 + lg;
      uint4 v = *(const uint4*)(Sp2 + swz128(r, li * 8));
      *(uint4*)(aoG + (R0 + t * 16 + r) * DD + li * 8) = v;
    }
  }
}

// ============================ KERNEL B2: LN2+FFN+out =======================
// Two tiles per wave, stage-interleaved. LN2 stats recomputed from bf16 x2.
__global__ __launch_bounds__(64)
void tail_b(const unsigned short* __restrict__ aoG,
            const float* __restrict__ g2, const float* __restrict__ b2,
            const unsigned short* __restrict__ wf1t, const float* __restrict__ bf1,
            const unsigned short* __restrict__ wf2t, const float* __restrict__ bf2,
            float* __restrict__ out) {
  __shared__ __align__(16) unsigned short smem[8192];  // 16 KB: 2x(Sp+Sp2)
  const int lane = threadIdx.x & 63;
  const int lg = lane >> 4;
  const int li = lane & 15;
  const int R0 = blockIdx.x * 32;

  float4 gA = *(const float4*)(g2 + li * 8);
  float4 gB = *(const float4*)(g2 + li * 8 + 4);
  float4 bA = *(const float4*)(b2 + li * 8);
  float4 bB = *(const float4*)(b2 + li * 8 + 4);

  // Phase 1 (both tiles): load x2 rows, park in Sp2, LN2 -> Xn2 in Sp.
  #pragma unroll
  for (int t = 0; t < 2; ++t) {
    unsigned short* Sp  = smem + t * 4096;
    unsigned short* Sp2 = smem + t * 4096 + 2048;
    const int R = R0 + t * 16;
    #pragma unroll
    for (int p = 0; p < 4; ++p) {
      int tr = p * 4 + lg;
      uint4 v = *(const uint4*)(aoG + (R + tr) * DD + li * 8);
      *(uint4*)(Sp2 + swz128(tr, li * 8)) = v;
      float f0 = bf2f((unsigned short)v.x),  f1 = bf2f((unsigned short)(v.x >> 16));
      float f2v = bf2f((unsigned short)v.y), f3 = bf2f((unsigned short)(v.y >> 16));
      float f4 = bf2f((unsigned short)v.z),  f5 = bf2f((unsigned short)(v.z >> 16));
      float f6 = bf2f((unsigned short)v.w),  f7 = bf2f((unsigned short)(v.w >> 16));
      float s1 = f0 + f1 + f2v + f3 + f4 + f5 + f6 + f7;
      float s2 = f0 * f0 + f1 * f1 + f2v * f2v + f3 * f3 + f4 * f4 + f5 * f5 + f6 * f6 + f7 * f7;
      s1 = red16(s1); s2 = red16(s2);
      float mean = s1 * (1.0f / 128.0f);
      float var = fmaxf((s2 - s1 * mean) * (1.0f / 127.0f), 0.0f);  // ddof=1
      float iv = 1.0f / (sqrtf(var) + 1e-6f);
      unsigned o01 = cvtpk(gA.x * (f0 - mean) * iv + bA.x, gA.y * (f1 - mean) * iv + bA.y);
      unsigned o23 = cvtpk(gA.z * (f2v - mean) * iv + bA.z, gA.w * (f3 - mean) * iv + bA.w);
      unsigned o45 = cvtpk(gB.x * (f4 - mean) * iv + bB.x, gB.y * (f5 - mean) * iv + bB.y);
      unsigned o67 = cvtpk(gB.z * (f6 - mean) * iv + bB.z, gB.w * (f7 - mean) * iv + bB.w);
      *(uint4*)(Sp + swz128(tr, li * 8)) = (uint4){o01, o23, o45, o67};
    }
  }

  // F1 (both tiles); af from Sp (Xn2) before epilogues overwrite
  bf16x8 afT[2][4];
  #pragma unroll
  for (int t = 0; t < 2; ++t) {
    unsigned short* Sp = smem + t * 4096;
    #pragma unroll
    for (int kk = 0; kk < 4; ++kk)
      afT[t][kk] = *(const bf16x8*)(Sp + swz128(li, kk * 32 + lg * 8));
  }
  #pragma unroll
  for (int t = 0; t < 2; ++t) {
    unsigned short* Sp = smem + t * 4096;
    #pragma unroll
    for (int h = 0; h < 2; ++h) {
      f32x4 acc[4];
      #pragma unroll
      for (int i = 0; i < 4; ++i) acc[i] = (f32x4){0, 0, 0, 0};
      #pragma unroll
      for (int kk = 0; kk < 4; ++kk)
        #pragma unroll
        for (int ct = 0; ct < 4; ++ct)
          acc[ct] = __builtin_amdgcn_mfma_f32_16x16x32_bf16(
              afT[t][kk],
              *(const bf16x8*)(wf1t + (h * 64 + ct * 16 + li) * 128 + kk * 32 + lg * 8),
              acc[ct], 0, 0, 0);
      #pragma unroll
      for (int ct = 0; ct < 4; ++ct) {
        int col = h * 64 + ct * 16 + li;
        float bv = bf1[col];
        unsigned p01 = cvtpk(fmaxf(acc[ct][0] + bv, 0.0f), fmaxf(acc[ct][1] + bv, 0.0f));
        unsigned p23 = cvtpk(fmaxf(acc[ct][2] + bv, 0.0f), fmaxf(acc[ct][3] + bv, 0.0f));
        Sp[swz128(lg * 4 + 0, col)] = (unsigned short)p01;
        Sp[swz128(lg * 4 + 1, col)] = (unsigned short)(p01 >> 16);
        Sp[swz128(lg * 4 + 2, col)] = (unsigned short)p23;
        Sp[swz128(lg * 4 + 3, col)] = (unsigned short)(p23 >> 16);
      }
    }
  }

  // F2 (both tiles) + final residual from Sp2
  #pragma unroll
  for (int t = 0; t < 2; ++t) {
    unsigned short* Sp = smem + t * 4096;
    #pragma unroll
    for (int kk = 0; kk < 4; ++kk)
      afT[t][kk] = *(const bf16x8*)(Sp + swz128(li, kk * 32 + lg * 8));
  }
  #pragma unroll
  for (int t = 0; t < 2; ++t) {
    unsigned short* Sp2 = smem + t * 4096 + 2048;
    const int R = R0 + t * 16;
    #pragma unroll
    for (int h = 0; h < 2; ++h) {
      f32x4 acc[4];
      #pragma unroll
      for (int i = 0; i < 4; ++i) acc[i] = (f32x4){0, 0, 0, 0};
      #pragma unroll
      for (int kk = 0; kk < 4; ++kk)
        #pragma unroll
        for (int ct = 0; ct < 4; ++ct)
          acc[ct] = __builtin_amdgcn_mfma_f32_16x16x32_bf16(
              afT[t][kk],
              *(const bf16x8*)(wf2t + (h * 64 + ct * 16 + li) * 128 + kk * 32 + lg * 8),
              acc[ct], 0, 0, 0);
      #pragma unroll
      for (int ct = 0; ct < 4; ++ct) {
        int col = h * 64 + ct * 16 + li;
        float bv = bf2[col];
        #pragma unroll
        for (int r = 0; r < 4; ++r) {
          float x2v = bf2f(Sp2[swz128(lg * 4 + r, col)]);
          out[(R + lg * 4 + r) * DD + col] = x2v + fmaxf(acc[ct][r] + bv, 0.0f);
        }
      }
    }
  }
}

extern "C" void kernel_launch(void* const* d_in, const int* in_sizes, int n_in,
                              void* d_out, int out_size, void* d_ws, size_t ws_size,
                              hipStream_t stream) {
  const float* x   = (const float*)d_in[0];
  const float* ste = (const float*)d_in[1];
  const float* g1 = (const float*)d_in[3];
  const float* b1 = (const float*)d_in[4];
  const float* g2 = (const float*)d_in[5];
  const float* b2 = (const float*)d_in[6];
  const float* Wq = (const float*)d_in[7];   const float* bq  = (const float*)d_in[8];
  const float* Wk = (const float*)d_in[9];   const float* bk  = (const float*)d_in[10];
  const float* Wv = (const float*)d_in[11];  const float* bv  = (const float*)d_in[12];
  const float* Wo1 = (const float*)d_in[13]; const float* bo1 = (const float*)d_in[14];
  const float* Wo2 = (const float*)d_in[15]; const float* bo2 = (const float*)d_in[16];
  const float* Wf1 = (const float*)d_in[17]; const float* bf1 = (const float*)d_in[18];
  const float* Wf2 = (const float*)d_in[19]; const float* bf2 = (const float*)d_in[20];
  float* out = (float*)d_out;

  unsigned short* wsu = (unsigned short*)d_ws;
  unsigned short* wq_t  = wsu;             // [128][256]
  unsigned short* wk_t  = wsu + 32768;
  unsigned short* wv_t  = wsu + 65536;
  unsigned short* wo1_t = wsu + 98304;     // [128][128]
  unsigned short* wo2_t = wsu + 114688;
  unsigned short* wf1_t = wsu + 131072;
  unsigned short* wf2_t = wsu + 147456;
  unsigned short* ao    = wsu + 163840;    // [B*T*N][128] bf16 = 64 MB (AO, then x2)

  hipLaunchKernelGGL(wprep, dim3(128), dim3(256), 0, stream, Wq, wq_t, 256, 128);
  hipLaunchKernelGGL(wprep, dim3(128), dim3(256), 0, stream, Wk, wk_t, 256, 128);
  hipLaunchKernelGGL(wprep, dim3(128), dim3(256), 0, stream, Wv, wv_t, 256, 128);
  hipLaunchKernelGGL(wprep, dim3(64), dim3(256), 0, stream, Wo1, wo1_t, 128, 128);
  hipLaunchKernelGGL(wprep, dim3(64), dim3(256), 0, stream, Wo2, wo2_t, 128, 128);
  hipLaunchKernelGGL(wprep, dim3(64), dim3(256), 0, stream, Wf1, wf1_t, 128, 128);
  hipLaunchKernelGGL(wprep, dim3(64), dim3(256), 0, stream, Wf2, wf2_t, 128, 128);

  hipLaunchKernelGGL(attn_head, dim3(8 * NN), dim3(512), 0, stream,
                     x, ste, g1, b1, wq_t, bq, wk_t, bk, wv_t, bv, ao);
  hipLaunchKernelGGL(tail_a, dim3(8 * TT * NN / 32), dim3(64), 0, stream,
                     ao, x, wo1_t, bo1, wo2_t, bo2);
  hipLaunchKernelGGL(tail_b, dim3(8 * TT * NN / 32), dim3(64), 0, stream,
                     ao, g2, b2, wf1_t, bf1, wf2_t, bf2, out);
}

// Round 20
// 422.766 us; speedup vs baseline: 1.1241x; 1.1241x over previous
//
#include <hip/hip_runtime.h>

#define TT 64
#define NN 512
#define DD 128

typedef __attribute__((ext_vector_type(8))) short bf16x8;
typedef __attribute__((ext_vector_type(4))) float f32x4;

__device__ __forceinline__ unsigned cvtpk(float lo, float hi) {
  unsigned r;
  asm("v_cvt_pk_bf16_f32 %0, %1, %2" : "=v"(r) : "v"(lo), "v"(hi));
  return r;
}

__device__ __forceinline__ float bf2f(unsigned short v) {
  return __uint_as_float((unsigned)v << 16);
}

// XOR-swizzled LDS index helpers (units: unsigned short elements).
__device__ __forceinline__ int swz128(int row, int col) {
  return row * 128 + (((col >> 3) ^ (row & 15)) << 3) + (col & 7);
}
__device__ __forceinline__ int swz64(int row, int col) {
  return row * 64 + (((col >> 3) ^ (row & 7)) << 3) + (col & 7);
}

// Barrier with LDS-only drain: global loads stay in flight across it.
__device__ __forceinline__ void bar() {
  asm volatile("s_waitcnt lgkmcnt(0)" ::: "memory");
  __builtin_amdgcn_s_barrier();
  asm volatile("" ::: "memory");
}

// 16-lane (DPP-row) sum via row_ror butterflies — VALU pipe, no LDS traffic.
__device__ __forceinline__ float red16(float s) {
  int t;
  t = __builtin_amdgcn_update_dpp(0, __float_as_int(s), 0x121, 0xf, 0xf, false);
  s += __int_as_float(t);
  t = __builtin_amdgcn_update_dpp(0, __float_as_int(s), 0x122, 0xf, 0xf, false);
  s += __int_as_float(t);
  t = __builtin_amdgcn_update_dpp(0, __float_as_int(s), 0x124, 0xf, 0xf, false);
  s += __int_as_float(t);
  t = __builtin_amdgcn_update_dpp(0, __float_as_int(s), 0x128, 0xf, 0xf, false);
  s += __int_as_float(t);
  return s;
}

// transpose fp32 [K][N] -> bf16 [N][K]
__global__ void wprep(const float* __restrict__ src, unsigned short* __restrict__ dst,
                      int K, int Nn) {
  int idx = blockIdx.x * 256 + threadIdx.x;
  if (idx >= K * Nn) return;
  int n = idx / K, k = idx - n * K;
  float f = src[k * Nn + n];
  unsigned u = __float_as_uint(f);
  u += 0x7fffu + ((u >> 16) & 1u);
  dst[idx] = (unsigned short)(u >> 16);
}

#define KSCL 0.36067376022224085f   // 0.25 * log2(e), folded into K epilogue

// ============================ KERNEL A =====================================
// LN1 + col-strip QKV + wave-local causal attention -> AO (bf16) to global.
__global__ __launch_bounds__(512, 4)
void attn_head(const float* __restrict__ x_in, const float* __restrict__ ste,
               const float* __restrict__ g1, const float* __restrict__ b1,
               const unsigned short* __restrict__ wqt, const float* __restrict__ bq,
               const unsigned short* __restrict__ wkt, const float* __restrict__ bk,
               const unsigned short* __restrict__ wvt, const float* __restrict__ bv,
               unsigned short* __restrict__ aoG) {
  __shared__ __align__(16) unsigned short smem[32768];  // 64 KB

  const int tid = threadIdx.x;
  const int lane = tid & 63;
  const int w  = tid >> 6;         // wave 0..7
  const int lg = lane >> 4;        // 0..3
  const int li = lane & 15;
  const int hc = w * 16;           // col-strip base == head base

  const int blk = blockIdx.x;
  const int b = blk >> 9;          // N=512
  const int n = blk & 511;
  const int rs = NN * DD;
  const float* xbase = x_in + (b * TT * NN + n) * DD;
  const float* sbase = ste + (b * TT * NN + n) * DD;

  unsigned short* X2s = smem;
  unsigned short* Qb  = smem;
  unsigned short* AOb = smem + 8192;
  unsigned short* Kb  = smem + 16384;
  unsigned short* Vt  = smem + 24576;

  #define SWZ256(row, col) ((row) * 256 + ((((col) >> 3) ^ ((row) & 15)) << 3) + ((col) & 7))

  // ---------------- LN1 + STE -> X2 (all input loads hoisted) --------------
  {
    const int t0 = w * 8 + lg;
    const float* xr0 = xbase + t0 * rs + li * 8;
    const float* xr1 = xbase + (t0 + 4) * rs + li * 8;
    const float* sr0 = sbase + t0 * rs + li * 8;
    const float* sr1 = sbase + (t0 + 4) * rs + li * 8;
    float4 xA0 = *(const float4*)(xr0);
    float4 xB0 = *(const float4*)(xr0 + 4);
    float4 xA1 = *(const float4*)(xr1);
    float4 xB1 = *(const float4*)(xr1 + 4);
    float4 sA0 = *(const float4*)(sr0);
    float4 sB0 = *(const float4*)(sr0 + 4);
    float4 sA1 = *(const float4*)(sr1);
    float4 sB1 = *(const float4*)(sr1 + 4);
    float4 gA = *(const float4*)(g1 + li * 8);
    float4 gB = *(const float4*)(g1 + li * 8 + 4);
    float4 bA = *(const float4*)(b1 + li * 8);
    float4 bB = *(const float4*)(b1 + li * 8 + 4);

    {  // row t0
      float s1 = xA0.x + xA0.y + xA0.z + xA0.w + xB0.x + xB0.y + xB0.z + xB0.w;
      float s2 = xA0.x * xA0.x + xA0.y * xA0.y + xA0.z * xA0.z + xA0.w * xA0.w +
                 xB0.x * xB0.x + xB0.y * xB0.y + xB0.z * xB0.z + xB0.w * xB0.w;
      s1 = red16(s1); s2 = red16(s2);
      float mean = s1 * (1.0f / 128.0f);
      float var = fmaxf((s2 - s1 * mean) * (1.0f / 127.0f), 0.0f);  // ddof=1
      float inv = 1.0f / (sqrtf(var) + 1e-6f);
      unsigned o01 = cvtpk(gA.x * (xA0.x - mean) * inv + bA.x, gA.y * (xA0.y - mean) * inv + bA.y);
      unsigned o23 = cvtpk(gA.z * (xA0.z - mean) * inv + bA.z, gA.w * (xA0.w - mean) * inv + bA.w);
      unsigned o45 = cvtpk(gB.x * (xB0.x - mean) * inv + bB.x, gB.y * (xB0.y - mean) * inv + bB.y);
      unsigned o67 = cvtpk(gB.z * (xB0.z - mean) * inv + bB.z, gB.w * (xB0.w - mean) * inv + bB.w);
      *(uint4*)(X2s + SWZ256(t0, li * 8)) = (uint4){o01, o23, o45, o67};
    }
    {  // row t0+4
      float s1 = xA1.x + xA1.y + xA1.z + xA1.w + xB1.x + xB1.y + xB1.z + xB1.w;
      float s2 = xA1.x * xA1.x + xA1.y * xA1.y + xA1.z * xA1.z + xA1.w * xA1.w +
                 xB1.x * xB1.x + xB1.y * xB1.y + xB1.z * xB1.z + xB1.w * xB1.w;
      s1 = red16(s1); s2 = red16(s2);
      float mean = s1 * (1.0f / 128.0f);
      float var = fmaxf((s2 - s1 * mean) * (1.0f / 127.0f), 0.0f);
      float inv = 1.0f / (sqrtf(var) + 1e-6f);
      unsigned o01 = cvtpk(gA.x * (xA1.x - mean) * inv + bA.x, gA.y * (xA1.y - mean) * inv + bA.y);
      unsigned o23 = cvtpk(gA.z * (xA1.z - mean) * inv + bA.z, gA.w * (xA1.w - mean) * inv + bA.w);
      unsigned o45 = cvtpk(gB.x * (xB1.x - mean) * inv + bB.x, gB.y * (xB1.y - mean) * inv + bB.y);
      unsigned o67 = cvtpk(gB.z * (xB1.z - mean) * inv + bB.z, gB.w * (xB1.w - mean) * inv + bB.w);
      *(uint4*)(X2s + SWZ256(t0 + 4, li * 8)) = (uint4){o01, o23, o45, o67};
    }
    *(uint4*)(X2s + SWZ256(t0, 128 + li * 8)) =
        (uint4){cvtpk(sA0.x, sA0.y), cvtpk(sA0.z, sA0.w), cvtpk(sB0.x, sB0.y), cvtpk(sB0.z, sB0.w)};
    *(uint4*)(X2s + SWZ256(t0 + 4, 128 + li * 8)) =
        (uint4){cvtpk(sA1.x, sA1.y), cvtpk(sA1.z, sA1.w), cvtpk(sB1.x, sB1.y), cvtpk(sB1.z, sB1.w)};
  }

  bar();  // B0: X2 visible

  // ---------------- V-pass (cols hc..hc+15), immediate epi -> Vt -----------
  {
    const unsigned short* vB = wvt + hc * 256;
    f32x4 va[4];
    #pragma unroll
    for (int rg = 0; rg < 4; ++rg) va[rg] = (f32x4){0, 0, 0, 0};
    #pragma unroll
    for (int kk = 0; kk < 8; ++kk) {
      bf16x8 bc = *(const bf16x8*)(vB + li * 256 + kk * 32 + lg * 8);
      #pragma unroll
      for (int rg = 0; rg < 4; ++rg) {
        bf16x8 af = *(const bf16x8*)(X2s + SWZ256(rg * 16 + li, kk * 32 + lg * 8));
        va[rg] = __builtin_amdgcn_mfma_f32_16x16x32_bf16(af, bc, va[rg], 0, 0, 0);
      }
    }
    float bvv = bv[hc + li];
    int d = hc + li;
    #pragma unroll
    for (int rg = 0; rg < 4; ++rg) {
      float v0 = fmaxf(va[rg][0] + bvv, 0.0f);
      float v1 = fmaxf(va[rg][1] + bvv, 0.0f);
      float v2 = fmaxf(va[rg][2] + bvv, 0.0f);
      float v3 = fmaxf(va[rg][3] + bvv, 0.0f);
      uint2 pv; pv.x = cvtpk(v0, v1); pv.y = cvtpk(v2, v3);
      *(uint2*)(Vt + swz64(d, rg * 16 + lg * 4)) = pv;
    }
  }

  // ---------------- K-pass (cols hc..hc+15), immediate epi -> Kb -----------
  {
    const unsigned short* kB = wkt + hc * 256;
    f32x4 ka[4];
    #pragma unroll
    for (int rg = 0; rg < 4; ++rg) ka[rg] = (f32x4){0, 0, 0, 0};
    #pragma unroll
    for (int kk = 0; kk < 8; ++kk) {
      bf16x8 bc = *(const bf16x8*)(kB + li * 256 + kk * 32 + lg * 8);
      #pragma unroll
      for (int rg = 0; rg < 4; ++rg) {
        bf16x8 af = *(const bf16x8*)(X2s + SWZ256(rg * 16 + li, kk * 32 + lg * 8));
        ka[rg] = __builtin_amdgcn_mfma_f32_16x16x32_bf16(af, bc, ka[rg], 0, 0, 0);
      }
    }
    float bkv = bk[hc + li];
    int col = hc + li;
    #pragma unroll
    for (int rg = 0; rg < 4; ++rg) {
      float k0 = fmaxf(ka[rg][0] + bkv, 0.0f) * KSCL;
      float k1 = fmaxf(ka[rg][1] + bkv, 0.0f) * KSCL;
      float k2 = fmaxf(ka[rg][2] + bkv, 0.0f) * KSCL;
      float k3 = fmaxf(ka[rg][3] + bkv, 0.0f) * KSCL;
      unsigned p01 = cvtpk(k0, k1), p23 = cvtpk(k2, k3);
      Kb[swz128(rg * 16 + lg * 4 + 0, col)] = (unsigned short)p01;
      Kb[swz128(rg * 16 + lg * 4 + 1, col)] = (unsigned short)(p01 >> 16);
      Kb[swz128(rg * 16 + lg * 4 + 2, col)] = (unsigned short)p23;
      Kb[swz128(rg * 16 + lg * 4 + 3, col)] = (unsigned short)(p23 >> 16);
    }
  }

  // ---------------- Q-pass (cols hc..hc+15) --------------------------------
  f32x4 qa[4];
  #pragma unroll
  for (int rg = 0; rg < 4; ++rg) qa[rg] = (f32x4){0, 0, 0, 0};
  {
    const unsigned short* qB = wqt + hc * 256;
    #pragma unroll
    for (int kk = 0; kk < 8; ++kk) {
      bf16x8 bc = *(const bf16x8*)(qB + li * 256 + kk * 32 + lg * 8);
      #pragma unroll
      for (int rg = 0; rg < 4; ++rg) {
        bf16x8 af = *(const bf16x8*)(X2s + SWZ256(rg * 16 + li, kk * 32 + lg * 8));
        qa[rg] = __builtin_amdgcn_mfma_f32_16x16x32_bf16(af, bc, qa[rg], 0, 0, 0);
      }
    }
  }

  bar();  // B0e: ALL X2 reads done -> Qb/AOb overlays live

  // Q epilogue -> Qb (own col strip; consumed only by this wave)
  {
    float bqv = bq[hc + li];
    int col = hc + li;
    #pragma unroll
    for (int rg = 0; rg < 4; ++rg) {
      float v0 = fmaxf(qa[rg][0] + bqv, 0.0f);
      float v1 = fmaxf(qa[rg][1] + bqv, 0.0f);
      float v2 = fmaxf(qa[rg][2] + bqv, 0.0f);
      float v3 = fmaxf(qa[rg][3] + bqv, 0.0f);
      unsigned p01 = cvtpk(v0, v1), p23 = cvtpk(v2, v3);
      Qb[swz128(rg * 16 + lg * 4 + 0, col)] = (unsigned short)p01;
      Qb[swz128(rg * 16 + lg * 4 + 1, col)] = (unsigned short)(p01 >> 16);
      Qb[swz128(rg * 16 + lg * 4 + 2, col)] = (unsigned short)p23;
      Qb[swz128(rg * 16 + lg * 4 + 3, col)] = (unsigned short)(p23 >> 16);
    }
  }

  // ---------------- causal attention, head w (all strips wave-local) -------
  {
    const bf16x8 zf = (bf16x8){0, 0, 0, 0, 0, 0, 0, 0};
    bf16x8 kf[4], vf[2];
    #pragma unroll
    for (int pt = 0; pt < 4; ++pt)
      kf[pt] = (lg < 2) ? *(const bf16x8*)(Kb + swz128(pt * 16 + li, hc + lg * 8)) : zf;
    #pragma unroll
    for (int ks = 0; ks < 2; ++ks)
      vf[ks] = *(const bf16x8*)(Vt + swz64(hc + li, ks * 32 + lg * 8));

    #pragma unroll
    for (int qt = 0; qt < 4; ++qt) {
      bf16x8 qf = (lg < 2) ? *(const bf16x8*)(Qb + swz128(qt * 16 + li, hc + lg * 8)) : zf;
      f32x4 st[4];
      #pragma unroll
      for (int pt = 0; pt < 4; ++pt)
        if (pt <= qt)
          st[pt] = __builtin_amdgcn_mfma_f32_16x16x32_bf16(kf[pt], qf, (f32x4){0, 0, 0, 0}, 0, 0, 0);

      float ssum = 0.0f;
      unsigned pa[4], pb[4];
      #pragma unroll
      for (int pt = 0; pt < 4; ++pt) {
        if (pt > qt) { pa[pt] = 0; pb[pt] = 0; continue; }
        float e0 = exp2f(st[pt][0]);
        float e1 = exp2f(st[pt][1]);
        float e2 = exp2f(st[pt][2]);
        float e3 = exp2f(st[pt][3]);
        if (pt == qt) {  // diagonal tile: mask p_local > q_local
          e0 = (4 * lg + 0 > li) ? 0.0f : e0;
          e1 = (4 * lg + 1 > li) ? 0.0f : e1;
          e2 = (4 * lg + 2 > li) ? 0.0f : e2;
          e3 = (4 * lg + 3 > li) ? 0.0f : e3;
        }
        ssum += e0 + e1 + e2 + e3;
        pa[pt] = cvtpk(e0, e1);
        pb[pt] = cvtpk(e2, e3);
      }
      ssum += __shfl_xor(ssum, 16, 64);
      ssum += __shfl_xor(ssum, 32, 64);
      float rinv = 1.0f / ssum;

      f32x4 oa = (f32x4){0, 0, 0, 0};
      #pragma unroll
      for (int ks = 0; ks < 2; ++ks) {
        if (ks * 2 > qt) continue;
        unsigned x = pa[2 * ks], y = pa[2 * ks + 1];
        asm("v_permlane32_swap_b32 %0, %1" : "+v"(x), "+v"(y));
        asm("v_permlane16_swap_b32 %0, %1" : "+v"(x), "+v"(y));
        unsigned u2 = pb[2 * ks], v2 = pb[2 * ks + 1];
        asm("v_permlane32_swap_b32 %0, %1" : "+v"(u2), "+v"(v2));
        asm("v_permlane16_swap_b32 %0, %1" : "+v"(u2), "+v"(v2));
        union { unsigned uw[4]; bf16x8 h; } pu;
        pu.uw[0] = x; pu.uw[1] = u2; pu.uw[2] = y; pu.uw[3] = v2;
        oa = __builtin_amdgcn_mfma_f32_16x16x32_bf16(vf[ks], pu.h, oa, 0, 0, 0);
      }
      uint2 ov;
      ov.x = cvtpk(oa[0] * rinv, oa[1] * rinv);
      ov.y = cvtpk(oa[2] * rinv, oa[3] * rinv);
      *(uint2*)(AOb + swz128(qt * 16 + li, hc + lg * 4)) = ov;
    }
  }

  bar();  // B2: AO strips visible

  // Coalesced AO store: wave w -> rows w*8..w*8+7, 16 lanes x 16B per row
  #pragma unroll
  for (int pass = 0; pass < 2; ++pass) {
    int t = w * 8 + pass * 4 + lg;
    uint4 v = *(const uint4*)(AOb + swz128(t, li * 8));
    *(uint4*)(aoG + ((b * TT + t) * NN + n) * DD + li * 8) = v;
  }
  #undef SWZ256
}

// ============================ KERNEL B =====================================
// Barrier-free tail, HALF-WIDTH passes + LDS-parked x2. R15-verified best:
// VGPR 124, zero spills, tail 273 us. No launch-bounds forcing (R13/14/16:
// any cap below the ~124-reg live set converts registers to scratch at 3-5x
// cost; R16's (256,5) squeeze was the worst regression of the session).
__device__ __forceinline__ void epi4h(const f32x4 acc[4], const float* __restrict__ bias,
                                      unsigned short* Sp, int c0, int li, int lg) {
  #pragma unroll
  for (int ct = 0; ct < 4; ++ct) {
    int col = c0 + ct * 16 + li;
    float bv = bias[col];
    float v0 = fmaxf(acc[ct][0] + bv, 0.0f);
    float v1 = fmaxf(acc[ct][1] + bv, 0.0f);
    float v2 = fmaxf(acc[ct][2] + bv, 0.0f);
    float v3 = fmaxf(acc[ct][3] + bv, 0.0f);
    unsigned p01 = cvtpk(v0, v1), p23 = cvtpk(v2, v3);
    Sp[swz128(lg * 4 + 0, col)] = (unsigned short)p01;
    Sp[swz128(lg * 4 + 1, col)] = (unsigned short)(p01 >> 16);
    Sp[swz128(lg * 4 + 2, col)] = (unsigned short)p23;
    Sp[swz128(lg * 4 + 3, col)] = (unsigned short)(p23 >> 16);
  }
}

__global__ __launch_bounds__(256)
void tail_ffn(const unsigned short* __restrict__ aoG, const float* __restrict__ x_in,
              const float* __restrict__ g2, const float* __restrict__ b2,
              const unsigned short* __restrict__ wo1t, const float* __restrict__ bo1,
              const unsigned short* __restrict__ wo2t, const float* __restrict__ bo2,
              const unsigned short* __restrict__ wf1t, const float* __restrict__ bf1,
              const unsigned short* __restrict__ wf2t, const float* __restrict__ bf2,
              float* __restrict__ out) {
  __shared__ __align__(16) unsigned short smem[16384];  // 32 KB
  const int tid = threadIdx.x;
  const int lane = tid & 63;
  const int w  = tid >> 6;          // wave 0..3
  const int lg = lane >> 4;
  const int li = lane & 15;
  unsigned short* Sp  = smem + w * 4096;         // wave-private [16][128]
  unsigned short* Sp2 = smem + w * 4096 + 2048;  // wave-private x2 (bf16)
  const int R = blockIdx.x * 64 + w * 16;        // flat row base

  // ---- O1 (two 64-col halves) ----
  bf16x8 af4[4];
  #pragma unroll
  for (int kk = 0; kk < 4; ++kk)
    af4[kk] = *(const bf16x8*)(aoG + (R + li) * DD + kk * 32 + lg * 8);
  #pragma unroll
  for (int h = 0; h < 2; ++h) {
    f32x4 acc[4];
    #pragma unroll
    for (int i = 0; i < 4; ++i) acc[i] = (f32x4){0, 0, 0, 0};
    #pragma unroll
    for (int kk = 0; kk < 4; ++kk)
      #pragma unroll
      for (int ct = 0; ct < 4; ++ct)
        acc[ct] = __builtin_amdgcn_mfma_f32_16x16x32_bf16(
            af4[kk],
            *(const bf16x8*)(wo1t + (h * 64 + ct * 16 + li) * 128 + kk * 32 + lg * 8),
            acc[ct], 0, 0, 0);
    epi4h(acc, bo1, Sp, h * 64, li, lg);
  }

  // ---- O2 + residual (per half; xr loaded just-in-time) ----
  #pragma unroll
  for (int kk = 0; kk < 4; ++kk)
    af4[kk] = *(const bf16x8*)(Sp + swz128(li, kk * 32 + lg * 8));
  float s1p[4] = {0, 0, 0, 0}, s2p[4] = {0, 0, 0, 0};
  #pragma unroll
  for (int h = 0; h < 2; ++h) {
    float xrh[4][4];
    #pragma unroll
    for (int ct = 0; ct < 4; ++ct)
      #pragma unroll
      for (int r = 0; r < 4; ++r)
        xrh[ct][r] = x_in[(R + lg * 4 + r) * DD + h * 64 + ct * 16 + li];
    f32x4 acc[4];
    #pragma unroll
    for (int i = 0; i < 4; ++i) acc[i] = (f32x4){0, 0, 0, 0};
    #pragma unroll
    for (int kk = 0; kk < 4; ++kk)
      #pragma unroll
      for (int ct = 0; ct < 4; ++ct)
        acc[ct] = __builtin_amdgcn_mfma_f32_16x16x32_bf16(
            af4[kk],
            *(const bf16x8*)(wo2t + (h * 64 + ct * 16 + li) * 128 + kk * 32 + lg * 8),
            acc[ct], 0, 0, 0);
    // x2 = acc + bo2 + x ; accumulate LN2 partials; park x2 as bf16 in Sp2
    #pragma unroll
    for (int ct = 0; ct < 4; ++ct) {
      int col = h * 64 + ct * 16 + li;
      float bvv = bo2[col];
      float v0 = acc[ct][0] + bvv + xrh[ct][0];
      float v1 = acc[ct][1] + bvv + xrh[ct][1];
      float v2 = acc[ct][2] + bvv + xrh[ct][2];
      float v3 = acc[ct][3] + bvv + xrh[ct][3];
      s1p[0] += v0; s2p[0] += v0 * v0;
      s1p[1] += v1; s2p[1] += v1 * v1;
      s1p[2] += v2; s2p[2] += v2 * v2;
      s1p[3] += v3; s2p[3] += v3 * v3;
      unsigned p01 = cvtpk(v0, v1), p23 = cvtpk(v2, v3);
      Sp2[swz128(lg * 4 + 0, col)] = (unsigned short)p01;
      Sp2[swz128(lg * 4 + 1, col)] = (unsigned short)(p01 >> 16);
      Sp2[swz128(lg * 4 + 2, col)] = (unsigned short)p23;
      Sp2[swz128(lg * 4 + 3, col)] = (unsigned short)(p23 >> 16);
    }
  }

  // ---- LN2 (wave-local; stats from fp32 partials) ----
  float mean_[4], inv_[4];
  #pragma unroll
  for (int r = 0; r < 4; ++r) {
    float s1 = red16(s1p[r]);
    float s2 = red16(s2p[r]);
    float mean = s1 * (1.0f / 128.0f);
    float var = fmaxf((s2 - s1 * mean) * (1.0f / 127.0f), 0.0f);  // ddof=1
    mean_[r] = mean;
    inv_[r] = 1.0f / (sqrtf(var) + 1e-6f);
  }
  // Xn2 -> Sp (x2 read back from Sp2; same-wave DS in-order)
  #pragma unroll
  for (int ct = 0; ct < 8; ++ct) {
    int col = ct * 16 + li;
    float gv = g2[col], bv2 = b2[col];
    float x0 = bf2f(Sp2[swz128(lg * 4 + 0, col)]);
    float x1 = bf2f(Sp2[swz128(lg * 4 + 1, col)]);
    float x2v = bf2f(Sp2[swz128(lg * 4 + 2, col)]);
    float x3 = bf2f(Sp2[swz128(lg * 4 + 3, col)]);
    unsigned p01 = cvtpk(gv * (x0 - mean_[0]) * inv_[0] + bv2,
                         gv * (x1 - mean_[1]) * inv_[1] + bv2);
    unsigned p23 = cvtpk(gv * (x2v - mean_[2]) * inv_[2] + bv2,
                         gv * (x3 - mean_[3]) * inv_[3] + bv2);
    Sp[swz128(lg * 4 + 0, col)] = (unsigned short)p01;
    Sp[swz128(lg * 4 + 1, col)] = (unsigned short)(p01 >> 16);
    Sp[swz128(lg * 4 + 2, col)] = (unsigned short)p23;
    Sp[swz128(lg * 4 + 3, col)] = (unsigned short)(p23 >> 16);
  }

  // ---- F1 (two halves; af4 read from Sp=Xn2 before Hf overwrites) ----
  #pragma unroll
  for (int kk = 0; kk < 4; ++kk)
    af4[kk] = *(const bf16x8*)(Sp + swz128(li, kk * 32 + lg * 8));
  #pragma unroll
  for (int h = 0; h < 2; ++h) {
    f32x4 acc[4];
    #pragma unroll
    for (int i = 0; i < 4; ++i) acc[i] = (f32x4){0, 0, 0, 0};
    #pragma unroll
    for (int kk = 0; kk < 4; ++kk)
      #pragma unroll
      for (int ct = 0; ct < 4; ++ct)
        acc[ct] = __builtin_amdgcn_mfma_f32_16x16x32_bf16(
            af4[kk],
            *(const bf16x8*)(wf1t + (h * 64 + ct * 16 + li) * 128 + kk * 32 + lg * 8),
            acc[ct], 0, 0, 0);
    epi4h(acc, bf1, Sp, h * 64, li, lg);
  }

  // ---- F2 (two halves) + final residual from Sp2 ----
  #pragma unroll
  for (int kk = 0; kk < 4; ++kk)
    af4[kk] = *(const bf16x8*)(Sp + swz128(li, kk * 32 + lg * 8));
  #pragma unroll
  for (int h = 0; h < 2; ++h) {
    f32x4 acc[4];
    #pragma unroll
    for (int i = 0; i < 4; ++i) acc[i] = (f32x4){0, 0, 0, 0};
    #pragma unroll
    for (int kk = 0; kk < 4; ++kk)
      #pragma unroll
      for (int ct = 0; ct < 4; ++ct)
        acc[ct] = __builtin_amdgcn_mfma_f32_16x16x32_bf16(
            af4[kk],
            *(const bf16x8*)(wf2t + (h * 64 + ct * 16 + li) * 128 + kk * 32 + lg * 8),
            acc[ct], 0, 0, 0);
    #pragma unroll
    for (int ct = 0; ct < 4; ++ct) {
      int col = h * 64 + ct * 16 + li;
      float bvv = bf2[col];
      #pragma unroll
      for (int r = 0; r < 4; ++r) {
        float x2v = bf2f(Sp2[swz128(lg * 4 + r, col)]);
        out[(R + lg * 4 + r) * DD + col] = x2v + fmaxf(acc[ct][r] + bvv, 0.0f);
      }
    }
  }
}

extern "C" void kernel_launch(void* const* d_in, const int* in_sizes, int n_in,
                              void* d_out, int out_size, void* d_ws, size_t ws_size,
                              hipStream_t stream) {
  const float* x   = (const float*)d_in[0];
  const float* ste = (const float*)d_in[1];
  const float* g1 = (const float*)d_in[3];
  const float* b1 = (const float*)d_in[4];
  const float* g2 = (const float*)d_in[5];
  const float* b2 = (const float*)d_in[6];
  const float* Wq = (const float*)d_in[7];   const float* bq  = (const float*)d_in[8];
  const float* Wk = (const float*)d_in[9];   const float* bk  = (const float*)d_in[10];
  const float* Wv = (const float*)d_in[11];  const float* bv  = (const float*)d_in[12];
  const float* Wo1 = (const float*)d_in[13]; const float* bo1 = (const float*)d_in[14];
  const float* Wo2 = (const float*)d_in[15]; const float* bo2 = (const float*)d_in[16];
  const float* Wf1 = (const float*)d_in[17]; const float* bf1 = (const float*)d_in[18];
  const float* Wf2 = (const float*)d_in[19]; const float* bf2 = (const float*)d_in[20];
  float* out = (float*)d_out;

  unsigned short* wsu = (unsigned short*)d_ws;
  unsigned short* wq_t  = wsu;             // [128][256]
  unsigned short* wk_t  = wsu + 32768;
  unsigned short* wv_t  = wsu + 65536;
  unsigned short* wo1_t = wsu + 98304;     // [128][128]
  unsigned short* wo2_t = wsu + 114688;
  unsigned short* wf1_t = wsu + 131072;
  unsigned short* wf2_t = wsu + 147456;
  unsigned short* ao    = wsu + 163840;    // [B*T*N][128] bf16 = 64 MB

  hipLaunchKernelGGL(wprep, dim3(128), dim3(256), 0, stream, Wq, wq_t, 256, 128);
  hipLaunchKernelGGL(wprep, dim3(128), dim3(256), 0, stream, Wk, wk_t, 256, 128);
  hipLaunchKernelGGL(wprep, dim3(128), dim3(256), 0, stream, Wv, wv_t, 256, 128);
  hipLaunchKernelGGL(wprep, dim3(64), dim3(256), 0, stream, Wo1, wo1_t, 128, 128);
  hipLaunchKernelGGL(wprep, dim3(64), dim3(256), 0, stream, Wo2, wo2_t, 128, 128);
  hipLaunchKernelGGL(wprep, dim3(64), dim3(256), 0, stream, Wf1, wf1_t, 128, 128);
  hipLaunchKernelGGL(wprep, dim3(64), dim3(256), 0, stream, Wf2, wf2_t, 128, 128);

  hipLaunchKernelGGL(attn_head, dim3(8 * NN), dim3(512), 0, stream,
                     x, ste, g1, b1, wq_t, bq, wk_t, bk, wv_t, bv, ao);
  hipLaunchKernelGGL(tail_ffn, dim3(8 * TT * NN / 64), dim3(256), 0, stream,
                     ao, x, g2, b2, wo1_t, bo1, wo2_t, bo2,
                     wf1_t, bf1, wf2_t, bf2, out);
}

// Round 21
// 281.193 us; speedup vs baseline: 1.6900x; 1.5035x over previous
//
#include <hip/hip_runtime.h>

#define TT 64
#define NN 512
#define DD 128

typedef __attribute__((ext_vector_type(8))) short bf16x8;
typedef __attribute__((ext_vector_type(4))) float f32x4;

__device__ __forceinline__ unsigned cvtpk(float lo, float hi) {
  unsigned r;
  asm("v_cvt_pk_bf16_f32 %0, %1, %2" : "=v"(r) : "v"(lo), "v"(hi));
  return r;
}

__device__ __forceinline__ float bf2f(unsigned short v) {
  return __uint_as_float((unsigned)v << 16);
}

// XOR-swizzled LDS index helpers (units: unsigned short elements).
__device__ __forceinline__ int swz128(int row, int col) {
  return row * 128 + (((col >> 3) ^ (row & 15)) << 3) + (col & 7);
}
__device__ __forceinline__ int swz64(int row, int col) {
  return row * 64 + (((col >> 3) ^ (row & 7)) << 3) + (col & 7);
}

// Barrier with LDS-only drain: global loads stay in flight across it.
__device__ __forceinline__ void bar() {
  asm volatile("s_waitcnt lgkmcnt(0)" ::: "memory");
  __builtin_amdgcn_s_barrier();
  asm volatile("" ::: "memory");
}

// 16-lane (DPP-row) sum via row_ror butterflies — VALU pipe, no LDS traffic.
__device__ __forceinline__ float red16(float s) {
  int t;
  t = __builtin_amdgcn_update_dpp(0, __float_as_int(s), 0x121, 0xf, 0xf, false);
  s += __int_as_float(t);
  t = __builtin_amdgcn_update_dpp(0, __float_as_int(s), 0x122, 0xf, 0xf, false);
  s += __int_as_float(t);
  t = __builtin_amdgcn_update_dpp(0, __float_as_int(s), 0x124, 0xf, 0xf, false);
  s += __int_as_float(t);
  t = __builtin_amdgcn_update_dpp(0, __float_as_int(s), 0x128, 0xf, 0xf, false);
  s += __int_as_float(t);
  return s;
}

// transpose fp32 [K][N] -> bf16 [N][K]
__global__ void wprep(const float* __restrict__ src, unsigned short* __restrict__ dst,
                      int K, int Nn) {
  int idx = blockIdx.x * 256 + threadIdx.x;
  if (idx >= K * Nn) return;
  int n = idx / K, k = idx - n * K;
  float f = src[k * Nn + n];
  unsigned u = __float_as_uint(f);
  u += 0x7fffu + ((u >> 16) & 1u);
  dst[idx] = (unsigned short)(u >> 16);
}

#define KSCL 0.36067376022224085f   // 0.25 * log2(e), folded into K epilogue

// ============================ KERNEL A =====================================
// LN1 + col-strip QKV + wave-local causal attention -> AO (bf16) to global.
__global__ __launch_bounds__(512, 4)
void attn_head(const float* __restrict__ x_in, const float* __restrict__ ste,
               const float* __restrict__ g1, const float* __restrict__ b1,
               const unsigned short* __restrict__ wqt, const float* __restrict__ bq,
               const unsigned short* __restrict__ wkt, const float* __restrict__ bk,
               const unsigned short* __restrict__ wvt, const float* __restrict__ bv,
               unsigned short* __restrict__ aoG) {
  __shared__ __align__(16) unsigned short smem[32768];  // 64 KB

  const int tid = threadIdx.x;
  const int lane = tid & 63;
  const int w  = tid >> 6;         // wave 0..7
  const int lg = lane >> 4;        // 0..3
  const int li = lane & 15;
  const int hc = w * 16;           // col-strip base == head base

  const int blk = blockIdx.x;
  const int b = blk >> 9;          // N=512
  const int n = blk & 511;
  const int rs = NN * DD;
  const float* xbase = x_in + (b * TT * NN + n) * DD;
  const float* sbase = ste + (b * TT * NN + n) * DD;

  unsigned short* X2s = smem;
  unsigned short* Qb  = smem;
  unsigned short* AOb = smem + 8192;
  unsigned short* Kb  = smem + 16384;
  unsigned short* Vt  = smem + 24576;

  #define SWZ256(row, col) ((row) * 256 + ((((col) >> 3) ^ ((row) & 15)) << 3) + ((col) & 7))

  // ---------------- LN1 + STE -> X2 (all input loads hoisted) --------------
  {
    const int t0 = w * 8 + lg;
    const float* xr0 = xbase + t0 * rs + li * 8;
    const float* xr1 = xbase + (t0 + 4) * rs + li * 8;
    const float* sr0 = sbase + t0 * rs + li * 8;
    const float* sr1 = sbase + (t0 + 4) * rs + li * 8;
    float4 xA0 = *(const float4*)(xr0);
    float4 xB0 = *(const float4*)(xr0 + 4);
    float4 xA1 = *(const float4*)(xr1);
    float4 xB1 = *(const float4*)(xr1 + 4);
    float4 sA0 = *(const float4*)(sr0);
    float4 sB0 = *(const float4*)(sr0 + 4);
    float4 sA1 = *(const float4*)(sr1);
    float4 sB1 = *(const float4*)(sr1 + 4);
    float4 gA = *(const float4*)(g1 + li * 8);
    float4 gB = *(const float4*)(g1 + li * 8 + 4);
    float4 bA = *(const float4*)(b1 + li * 8);
    float4 bB = *(const float4*)(b1 + li * 8 + 4);

    {  // row t0
      float s1 = xA0.x + xA0.y + xA0.z + xA0.w + xB0.x + xB0.y + xB0.z + xB0.w;
      float s2 = xA0.x * xA0.x + xA0.y * xA0.y + xA0.z * xA0.z + xA0.w * xA0.w +
                 xB0.x * xB0.x + xB0.y * xB0.y + xB0.z * xB0.z + xB0.w * xB0.w;
      s1 = red16(s1); s2 = red16(s2);
      float mean = s1 * (1.0f / 128.0f);
      float var = fmaxf((s2 - s1 * mean) * (1.0f / 127.0f), 0.0f);  // ddof=1
      float inv = 1.0f / (sqrtf(var) + 1e-6f);
      unsigned o01 = cvtpk(gA.x * (xA0.x - mean) * inv + bA.x, gA.y * (xA0.y - mean) * inv + bA.y);
      unsigned o23 = cvtpk(gA.z * (xA0.z - mean) * inv + bA.z, gA.w * (xA0.w - mean) * inv + bA.w);
      unsigned o45 = cvtpk(gB.x * (xB0.x - mean) * inv + bB.x, gB.y * (xB0.y - mean) * inv + bB.y);
      unsigned o67 = cvtpk(gB.z * (xB0.z - mean) * inv + bB.z, gB.w * (xB0.w - mean) * inv + bB.w);
      *(uint4*)(X2s + SWZ256(t0, li * 8)) = (uint4){o01, o23, o45, o67};
    }
    {  // row t0+4
      float s1 = xA1.x + xA1.y + xA1.z + xA1.w + xB1.x + xB1.y + xB1.z + xB1.w;
      float s2 = xA1.x * xA1.x + xA1.y * xA1.y + xA1.z * xA1.z + xA1.w * xA1.w +
                 xB1.x * xB1.x + xB1.y * xB1.y + xB1.z * xB1.z + xB1.w * xB1.w;
      s1 = red16(s1); s2 = red16(s2);
      float mean = s1 * (1.0f / 128.0f);
      float var = fmaxf((s2 - s1 * mean) * (1.0f / 127.0f), 0.0f);
      float inv = 1.0f / (sqrtf(var) + 1e-6f);
      unsigned o01 = cvtpk(gA.x * (xA1.x - mean) * inv + bA.x, gA.y * (xA1.y - mean) * inv + bA.y);
      unsigned o23 = cvtpk(gA.z * (xA1.z - mean) * inv + bA.z, gA.w * (xA1.w - mean) * inv + bA.w);
      unsigned o45 = cvtpk(gB.x * (xB1.x - mean) * inv + bB.x, gB.y * (xB1.y - mean) * inv + bB.y);
      unsigned o67 = cvtpk(gB.z * (xB1.z - mean) * inv + bB.z, gB.w * (xB1.w - mean) * inv + bB.w);
      *(uint4*)(X2s + SWZ256(t0 + 4, li * 8)) = (uint4){o01, o23, o45, o67};
    }
    *(uint4*)(X2s + SWZ256(t0, 128 + li * 8)) =
        (uint4){cvtpk(sA0.x, sA0.y), cvtpk(sA0.z, sA0.w), cvtpk(sB0.x, sB0.y), cvtpk(sB0.z, sB0.w)};
    *(uint4*)(X2s + SWZ256(t0 + 4, 128 + li * 8)) =
        (uint4){cvtpk(sA1.x, sA1.y), cvtpk(sA1.z, sA1.w), cvtpk(sB1.x, sB1.y), cvtpk(sB1.z, sB1.w)};
  }

  bar();  // B0: X2 visible

  // ---------------- V-pass (cols hc..hc+15), immediate epi -> Vt -----------
  {
    const unsigned short* vB = wvt + hc * 256;
    f32x4 va[4];
    #pragma unroll
    for (int rg = 0; rg < 4; ++rg) va[rg] = (f32x4){0, 0, 0, 0};
    #pragma unroll
    for (int kk = 0; kk < 8; ++kk) {
      bf16x8 bc = *(const bf16x8*)(vB + li * 256 + kk * 32 + lg * 8);
      #pragma unroll
      for (int rg = 0; rg < 4; ++rg) {
        bf16x8 af = *(const bf16x8*)(X2s + SWZ256(rg * 16 + li, kk * 32 + lg * 8));
        va[rg] = __builtin_amdgcn_mfma_f32_16x16x32_bf16(af, bc, va[rg], 0, 0, 0);
      }
    }
    float bvv = bv[hc + li];
    int d = hc + li;
    #pragma unroll
    for (int rg = 0; rg < 4; ++rg) {
      float v0 = fmaxf(va[rg][0] + bvv, 0.0f);
      float v1 = fmaxf(va[rg][1] + bvv, 0.0f);
      float v2 = fmaxf(va[rg][2] + bvv, 0.0f);
      float v3 = fmaxf(va[rg][3] + bvv, 0.0f);
      uint2 pv; pv.x = cvtpk(v0, v1); pv.y = cvtpk(v2, v3);
      *(uint2*)(Vt + swz64(d, rg * 16 + lg * 4)) = pv;
    }
  }

  // ---------------- K-pass (cols hc..hc+15), immediate epi -> Kb -----------
  {
    const unsigned short* kB = wkt + hc * 256;
    f32x4 ka[4];
    #pragma unroll
    for (int rg = 0; rg < 4; ++rg) ka[rg] = (f32x4){0, 0, 0, 0};
    #pragma unroll
    for (int kk = 0; kk < 8; ++kk) {
      bf16x8 bc = *(const bf16x8*)(kB + li * 256 + kk * 32 + lg * 8);
      #pragma unroll
      for (int rg = 0; rg < 4; ++rg) {
        bf16x8 af = *(const bf16x8*)(X2s + SWZ256(rg * 16 + li, kk * 32 + lg * 8));
        ka[rg] = __builtin_amdgcn_mfma_f32_16x16x32_bf16(af, bc, ka[rg], 0, 0, 0);
      }
    }
    float bkv = bk[hc + li];
    int col = hc + li;
    #pragma unroll
    for (int rg = 0; rg < 4; ++rg) {
      float k0 = fmaxf(ka[rg][0] + bkv, 0.0f) * KSCL;
      float k1 = fmaxf(ka[rg][1] + bkv, 0.0f) * KSCL;
      float k2 = fmaxf(ka[rg][2] + bkv, 0.0f) * KSCL;
      float k3 = fmaxf(ka[rg][3] + bkv, 0.0f) * KSCL;
      unsigned p01 = cvtpk(k0, k1), p23 = cvtpk(k2, k3);
      Kb[swz128(rg * 16 + lg * 4 + 0, col)] = (unsigned short)p01;
      Kb[swz128(rg * 16 + lg * 4 + 1, col)] = (unsigned short)(p01 >> 16);
      Kb[swz128(rg * 16 + lg * 4 + 2, col)] = (unsigned short)p23;
      Kb[swz128(rg * 16 + lg * 4 + 3, col)] = (unsigned short)(p23 >> 16);
    }
  }

  // ---------------- Q-pass (cols hc..hc+15) --------------------------------
  f32x4 qa[4];
  #pragma unroll
  for (int rg = 0; rg < 4; ++rg) qa[rg] = (f32x4){0, 0, 0, 0};
  {
    const unsigned short* qB = wqt + hc * 256;
    #pragma unroll
    for (int kk = 0; kk < 8; ++kk) {
      bf16x8 bc = *(const bf16x8*)(qB + li * 256 + kk * 32 + lg * 8);
      #pragma unroll
      for (int rg = 0; rg < 4; ++rg) {
        bf16x8 af = *(const bf16x8*)(X2s + SWZ256(rg * 16 + li, kk * 32 + lg * 8));
        qa[rg] = __builtin_amdgcn_mfma_f32_16x16x32_bf16(af, bc, qa[rg], 0, 0, 0);
      }
    }
  }

  bar();  // B0e: ALL X2 reads done -> Qb/AOb overlays live

  // Q epilogue -> Qb (own col strip; consumed only by this wave)
  {
    float bqv = bq[hc + li];
    int col = hc + li;
    #pragma unroll
    for (int rg = 0; rg < 4; ++rg) {
      float v0 = fmaxf(qa[rg][0] + bqv, 0.0f);
      float v1 = fmaxf(qa[rg][1] + bqv, 0.0f);
      float v2 = fmaxf(qa[rg][2] + bqv, 0.0f);
      float v3 = fmaxf(qa[rg][3] + bqv, 0.0f);
      unsigned p01 = cvtpk(v0, v1), p23 = cvtpk(v2, v3);
      Qb[swz128(rg * 16 + lg * 4 + 0, col)] = (unsigned short)p01;
      Qb[swz128(rg * 16 + lg * 4 + 1, col)] = (unsigned short)(p01 >> 16);
      Qb[swz128(rg * 16 + lg * 4 + 2, col)] = (unsigned short)p23;
      Qb[swz128(rg * 16 + lg * 4 + 3, col)] = (unsigned short)(p23 >> 16);
    }
  }

  // ---------------- causal attention, head w (all strips wave-local) -------
  {
    const bf16x8 zf = (bf16x8){0, 0, 0, 0, 0, 0, 0, 0};
    bf16x8 kf[4], vf[2];
    #pragma unroll
    for (int pt = 0; pt < 4; ++pt)
      kf[pt] = (lg < 2) ? *(const bf16x8*)(Kb + swz128(pt * 16 + li, hc + lg * 8)) : zf;
    #pragma unroll
    for (int ks = 0; ks < 2; ++ks)
      vf[ks] = *(const bf16x8*)(Vt + swz64(hc + li, ks * 32 + lg * 8));

    #pragma unroll
    for (int qt = 0; qt < 4; ++qt) {
      bf16x8 qf = (lg < 2) ? *(const bf16x8*)(Qb + swz128(qt * 16 + li, hc + lg * 8)) : zf;
      f32x4 st[4];
      #pragma unroll
      for (int pt = 0; pt < 4; ++pt)
        if (pt <= qt)
          st[pt] = __builtin_amdgcn_mfma_f32_16x16x32_bf16(kf[pt], qf, (f32x4){0, 0, 0, 0}, 0, 0, 0);

      float ssum = 0.0f;
      unsigned pa[4], pb[4];
      #pragma unroll
      for (int pt = 0; pt < 4; ++pt) {
        if (pt > qt) { pa[pt] = 0; pb[pt] = 0; continue; }
        float e0 = exp2f(st[pt][0]);
        float e1 = exp2f(st[pt][1]);
        float e2 = exp2f(st[pt][2]);
        float e3 = exp2f(st[pt][3]);
        if (pt == qt) {  // diagonal tile: mask p_local > q_local
          e0 = (4 * lg + 0 > li) ? 0.0f : e0;
          e1 = (4 * lg + 1 > li) ? 0.0f : e1;
          e2 = (4 * lg + 2 > li) ? 0.0f : e2;
          e3 = (4 * lg + 3 > li) ? 0.0f : e3;
        }
        ssum += e0 + e1 + e2 + e3;
        pa[pt] = cvtpk(e0, e1);
        pb[pt] = cvtpk(e2, e3);
      }
      ssum += __shfl_xor(ssum, 16, 64);
      ssum += __shfl_xor(ssum, 32, 64);
      float rinv = 1.0f / ssum;

      f32x4 oa = (f32x4){0, 0, 0, 0};
      #pragma unroll
      for (int ks = 0; ks < 2; ++ks) {
        if (ks * 2 > qt) continue;
        unsigned x = pa[2 * ks], y = pa[2 * ks + 1];
        asm("v_permlane32_swap_b32 %0, %1" : "+v"(x), "+v"(y));
        asm("v_permlane16_swap_b32 %0, %1" : "+v"(x), "+v"(y));
        unsigned u2 = pb[2 * ks], v2 = pb[2 * ks + 1];
        asm("v_permlane32_swap_b32 %0, %1" : "+v"(u2), "+v"(v2));
        asm("v_permlane16_swap_b32 %0, %1" : "+v"(u2), "+v"(v2));
        union { unsigned uw[4]; bf16x8 h; } pu;
        pu.uw[0] = x; pu.uw[1] = u2; pu.uw[2] = y; pu.uw[3] = v2;
        oa = __builtin_amdgcn_mfma_f32_16x16x32_bf16(vf[ks], pu.h, oa, 0, 0, 0);
      }
      uint2 ov;
      ov.x = cvtpk(oa[0] * rinv, oa[1] * rinv);
      ov.y = cvtpk(oa[2] * rinv, oa[3] * rinv);
      *(uint2*)(AOb + swz128(qt * 16 + li, hc + lg * 4)) = ov;
    }
  }

  bar();  // B2: AO strips visible

  // Coalesced AO store: wave w -> rows w*8..w*8+7, 16 lanes x 16B per row
  #pragma unroll
  for (int pass = 0; pass < 2; ++pass) {
    int t = w * 8 + pass * 4 + lg;
    uint4 v = *(const uint4*)(AOb + swz128(t, li * 8));
    *(uint4*)(aoG + ((b * TT + t) * NN + n) * DD + li * 8) = v;
  }
  #undef SWZ256
}

// ============================ KERNEL B =====================================
// Tail rebuilt in the HEAD's image: 8-wave blocks over 64 flat rows, each
// wave owns a 16-col strip per GEMM (B-frags loaded once, reused over 4
// row-groups; acc = 16 regs). Low VGPR (~70) + 48KB LDS -> 3 blocks/CU
// co-resident, cross-block overlap absorbs the 5 lgkm-barriers (head runs
// this exact pattern at 41% occupancy; R15-tail was stuck at 22% / VGPR 124).
__global__ __launch_bounds__(512)
void tail_ffn(const unsigned short* __restrict__ aoG, const float* __restrict__ x_in,
              const float* __restrict__ g2, const float* __restrict__ b2,
              const unsigned short* __restrict__ wo1t, const float* __restrict__ bo1,
              const unsigned short* __restrict__ wo2t, const float* __restrict__ bo2,
              const unsigned short* __restrict__ wf1t, const float* __restrict__ bf1,
              const unsigned short* __restrict__ wf2t, const float* __restrict__ bf2,
              float* __restrict__ out) {
  __shared__ __align__(16) unsigned short smem[24576];  // 48 KB
  const int tid = threadIdx.x;
  const int lane = tid & 63;
  const int w  = tid >> 6;          // wave 0..7
  const int lg = lane >> 4;
  const int li = lane & 15;
  const int hc = w * 16;            // col strip for GEMM passes
  const int R0 = blockIdx.x * 64;   // flat row base (B*T*N rows total)

  // Regions (16KB each, disjoint lifetimes):
  //  Ar [0,8192): AO, later Xn2        Br [8192,16384): H1, later Hf
  //  Cr [16384,24576): x2 (bf16, persists to final residual)
  unsigned short* Ar = smem;
  unsigned short* Br = smem + 8192;
  unsigned short* Cr = smem + 16384;

  // ---- stage AO[64][128] -> Ar (coalesced; wave w rows w*8..w*8+7) --------
  #pragma unroll
  for (int p = 0; p < 2; ++p) {
    int t = w * 8 + p * 4 + lg;
    uint4 v = *(const uint4*)(aoG + (R0 + t) * DD + li * 8);
    *(uint4*)(Ar + swz128(t, li * 8)) = v;
  }
  bar();  // AO visible

  // ---- O1 col-strip: H1[0:64][hc:hc+16] -> Br -----------------------------
  {
    f32x4 acc[4];
    #pragma unroll
    for (int i = 0; i < 4; ++i) acc[i] = (f32x4){0, 0, 0, 0};
    #pragma unroll
    for (int kk = 0; kk < 4; ++kk) {
      bf16x8 bc = *(const bf16x8*)(wo1t + (hc + li) * 128 + kk * 32 + lg * 8);
      #pragma unroll
      for (int rg = 0; rg < 4; ++rg) {
        bf16x8 af = *(const bf16x8*)(Ar + swz128(rg * 16 + li, kk * 32 + lg * 8));
        acc[rg] = __builtin_amdgcn_mfma_f32_16x16x32_bf16(af, bc, acc[rg], 0, 0, 0);
      }
    }
    float bvv = bo1[hc + li];
    int col = hc + li;
    #pragma unroll
    for (int rg = 0; rg < 4; ++rg) {
      unsigned p01 = cvtpk(fmaxf(acc[rg][0] + bvv, 0.0f), fmaxf(acc[rg][1] + bvv, 0.0f));
      unsigned p23 = cvtpk(fmaxf(acc[rg][2] + bvv, 0.0f), fmaxf(acc[rg][3] + bvv, 0.0f));
      Br[swz128(rg * 16 + lg * 4 + 0, col)] = (unsigned short)p01;
      Br[swz128(rg * 16 + lg * 4 + 1, col)] = (unsigned short)(p01 >> 16);
      Br[swz128(rg * 16 + lg * 4 + 2, col)] = (unsigned short)p23;
      Br[swz128(rg * 16 + lg * 4 + 3, col)] = (unsigned short)(p23 >> 16);
    }
  }
  bar();  // H1 visible; Ar reads done

  // ---- O2 col-strip + residual: x2 -> Cr ----------------------------------
  {
    f32x4 acc[4];
    #pragma unroll
    for (int i = 0; i < 4; ++i) acc[i] = (f32x4){0, 0, 0, 0};
    #pragma unroll
    for (int kk = 0; kk < 4; ++kk) {
      bf16x8 bc = *(const bf16x8*)(wo2t + (hc + li) * 128 + kk * 32 + lg * 8);
      #pragma unroll
      for (int rg = 0; rg < 4; ++rg) {
        bf16x8 af = *(const bf16x8*)(Br + swz128(rg * 16 + li, kk * 32 + lg * 8));
        acc[rg] = __builtin_amdgcn_mfma_f32_16x16x32_bf16(af, bc, acc[rg], 0, 0, 0);
      }
    }
    float bvv = bo2[hc + li];
    int col = hc + li;
    #pragma unroll
    for (int rg = 0; rg < 4; ++rg) {
      float x0 = x_in[(R0 + rg * 16 + lg * 4 + 0) * DD + col];
      float x1 = x_in[(R0 + rg * 16 + lg * 4 + 1) * DD + col];
      float x2v = x_in[(R0 + rg * 16 + lg * 4 + 2) * DD + col];
      float x3 = x_in[(R0 + rg * 16 + lg * 4 + 3) * DD + col];
      unsigned p01 = cvtpk(acc[rg][0] + bvv + x0, acc[rg][1] + bvv + x1);
      unsigned p23 = cvtpk(acc[rg][2] + bvv + x2v, acc[rg][3] + bvv + x3);
      Cr[swz128(rg * 16 + lg * 4 + 0, col)] = (unsigned short)p01;
      Cr[swz128(rg * 16 + lg * 4 + 1, col)] = (unsigned short)(p01 >> 16);
      Cr[swz128(rg * 16 + lg * 4 + 2, col)] = (unsigned short)p23;
      Cr[swz128(rg * 16 + lg * 4 + 3, col)] = (unsigned short)(p23 >> 16);
    }
  }
  bar();  // x2 visible

  // ---- LN2 (head-LN1 style: wave w re-reads rows w*8..w*8+7 full-width) ---
  {
    float4 gA = *(const float4*)(g2 + li * 8);
    float4 gB = *(const float4*)(g2 + li * 8 + 4);
    float4 bA = *(const float4*)(b2 + li * 8);
    float4 bB = *(const float4*)(b2 + li * 8 + 4);
    #pragma unroll
    for (int p = 0; p < 2; ++p) {
      int t = w * 8 + p * 4 + lg;
      uint4 v = *(const uint4*)(Cr + swz128(t, li * 8));
      float f0 = bf2f((unsigned short)v.x),  f1 = bf2f((unsigned short)(v.x >> 16));
      float f2v = bf2f((unsigned short)v.y), f3 = bf2f((unsigned short)(v.y >> 16));
      float f4 = bf2f((unsigned short)v.z),  f5 = bf2f((unsigned short)(v.z >> 16));
      float f6 = bf2f((unsigned short)v.w),  f7 = bf2f((unsigned short)(v.w >> 16));
      float s1 = f0 + f1 + f2v + f3 + f4 + f5 + f6 + f7;
      float s2 = f0 * f0 + f1 * f1 + f2v * f2v + f3 * f3 + f4 * f4 + f5 * f5 + f6 * f6 + f7 * f7;
      s1 = red16(s1); s2 = red16(s2);
      float mean = s1 * (1.0f / 128.0f);
      float var = fmaxf((s2 - s1 * mean) * (1.0f / 127.0f), 0.0f);  // ddof=1
      float iv = 1.0f / (sqrtf(var) + 1e-6f);
      unsigned o01 = cvtpk(gA.x * (f0 - mean) * iv + bA.x, gA.y * (f1 - mean) * iv + bA.y);
      unsigned o23 = cvtpk(gA.z * (f2v - mean) * iv + bA.z, gA.w * (f3 - mean) * iv + bA.w);
      unsigned o45 = cvtpk(gB.x * (f4 - mean) * iv + bB.x, gB.y * (f5 - mean) * iv + bB.y);
      unsigned o67 = cvtpk(gB.z * (f6 - mean) * iv + bB.z, gB.w * (f7 - mean) * iv + bB.w);
      *(uint4*)(Ar + swz128(t, li * 8)) = (uint4){o01, o23, o45, o67};  // Xn2
    }
  }
  bar();  // Xn2 visible

  // ---- F1 col-strip: Hf -> Br ---------------------------------------------
  {
    f32x4 acc[4];
    #pragma unroll
    for (int i = 0; i < 4; ++i) acc[i] = (f32x4){0, 0, 0, 0};
    #pragma unroll
    for (int kk = 0; kk < 4; ++kk) {
      bf16x8 bc = *(const bf16x8*)(wf1t + (hc + li) * 128 + kk * 32 + lg * 8);
      #pragma unroll
      for (int rg = 0; rg < 4; ++rg) {
        bf16x8 af = *(const bf16x8*)(Ar + swz128(rg * 16 + li, kk * 32 + lg * 8));
        acc[rg] = __builtin_amdgcn_mfma_f32_16x16x32_bf16(af, bc, acc[rg], 0, 0, 0);
      }
    }
    float bvv = bf1[hc + li];
    int col = hc + li;
    #pragma unroll
    for (int rg = 0; rg < 4; ++rg) {
      unsigned p01 = cvtpk(fmaxf(acc[rg][0] + bvv, 0.0f), fmaxf(acc[rg][1] + bvv, 0.0f));
      unsigned p23 = cvtpk(fmaxf(acc[rg][2] + bvv, 0.0f), fmaxf(acc[rg][3] + bvv, 0.0f));
      Br[swz128(rg * 16 + lg * 4 + 0, col)] = (unsigned short)p01;
      Br[swz128(rg * 16 + lg * 4 + 1, col)] = (unsigned short)(p01 >> 16);
      Br[swz128(rg * 16 + lg * 4 + 2, col)] = (unsigned short)p23;
      Br[swz128(rg * 16 + lg * 4 + 3, col)] = (unsigned short)(p23 >> 16);
    }
  }
  bar();  // Hf visible

  // ---- F2 col-strip + final residual (x2 from Cr) -> out ------------------
  {
    f32x4 acc[4];
    #pragma unroll
    for (int i = 0; i < 4; ++i) acc[i] = (f32x4){0, 0, 0, 0};
    #pragma unroll
    for (int kk = 0; kk < 4; ++kk) {
      bf16x8 bc = *(const bf16x8*)(wf2t + (hc + li) * 128 + kk * 32 + lg * 8);
      #pragma unroll
      for (int rg = 0; rg < 4; ++rg) {
        bf16x8 af = *(const bf16x8*)(Br + swz128(rg * 16 + li, kk * 32 + lg * 8));
        acc[rg] = __builtin_amdgcn_mfma_f32_16x16x32_bf16(af, bc, acc[rg], 0, 0, 0);
      }
    }
    float bvv = bf2[hc + li];
    int col = hc + li;
    #pragma unroll
    for (int rg = 0; rg < 4; ++rg) {
      #pragma unroll
      for (int r = 0; r < 4; ++r) {
        int row = rg * 16 + lg * 4 + r;
        float x2v = bf2f(Cr[swz128(row, col)]);
        out[(R0 + row) * DD + col] = x2v + fmaxf(acc[rg][r] + bvv, 0.0f);
      }
    }
  }
}

extern "C" void kernel_launch(void* const* d_in, const int* in_sizes, int n_in,
                              void* d_out, int out_size, void* d_ws, size_t ws_size,
                              hipStream_t stream) {
  const float* x   = (const float*)d_in[0];
  const float* ste = (const float*)d_in[1];
  const float* g1 = (const float*)d_in[3];
  const float* b1 = (const float*)d_in[4];
  const float* g2 = (const float*)d_in[5];
  const float* b2 = (const float*)d_in[6];
  const float* Wq = (const float*)d_in[7];   const float* bq  = (const float*)d_in[8];
  const float* Wk = (const float*)d_in[9];   const float* bk  = (const float*)d_in[10];
  const float* Wv = (const float*)d_in[11];  const float* bv  = (const float*)d_in[12];
  const float* Wo1 = (const float*)d_in[13]; const float* bo1 = (const float*)d_in[14];
  const float* Wo2 = (const float*)d_in[15]; const float* bo2 = (const float*)d_in[16];
  const float* Wf1 = (const float*)d_in[17]; const float* bf1 = (const float*)d_in[18];
  const float* Wf2 = (const float*)d_in[19]; const float* bf2 = (const float*)d_in[20];
  float* out = (float*)d_out;

  unsigned short* wsu = (unsigned short*)d_ws;
  unsigned short* wq_t  = wsu;             // [128][256]
  unsigned short* wk_t  = wsu + 32768;
  unsigned short* wv_t  = wsu + 65536;
  unsigned short* wo1_t = wsu + 98304;     // [128][128]
  unsigned short* wo2_t = wsu + 114688;
  unsigned short* wf1_t = wsu + 131072;
  unsigned short* wf2_t = wsu + 147456;
  unsigned short* ao    = wsu + 163840;    // [B*T*N][128] bf16 = 64 MB

  hipLaunchKernelGGL(wprep, dim3(128), dim3(256), 0, stream, Wq, wq_t, 256, 128);
  hipLaunchKernelGGL(wprep, dim3(128), dim3(256), 0, stream, Wk, wk_t, 256, 128);
  hipLaunchKernelGGL(wprep, dim3(128), dim3(256), 0, stream, Wv, wv_t, 256, 128);
  hipLaunchKernelGGL(wprep, dim3(64), dim3(256), 0, stream, Wo1, wo1_t, 128, 128);
  hipLaunchKernelGGL(wprep, dim3(64), dim3(256), 0, stream, Wo2, wo2_t, 128, 128);
  hipLaunchKernelGGL(wprep, dim3(64), dim3(256), 0, stream, Wf1, wf1_t, 128, 128);
  hipLaunchKernelGGL(wprep, dim3(64), dim3(256), 0, stream, Wf2, wf2_t, 128, 128);

  hipLaunchKernelGGL(attn_head, dim3(8 * NN), dim3(512), 0, stream,
                     x, ste, g1, b1, wq_t, bq, wk_t, bk, wv_t, bv, ao);
  hipLaunchKernelGGL(tail_ffn, dim3(8 * TT * NN / 64), dim3(512), 0, stream,
                     ao, x, g2, b2, wo1_t, bo1, wo2_t, bo2,
                     wf1_t, bf1, wf2_t, bf2, out);
}

// Round 22
// 280.645 us; speedup vs baseline: 1.6933x; 1.0020x over previous
//
#include <hip/hip_runtime.h>

#define TT 64
#define NN 512
#define DD 128

typedef __attribute__((ext_vector_type(8))) short bf16x8;
typedef __attribute__((ext_vector_type(4))) float f32x4;

__device__ __forceinline__ unsigned cvtpk(float lo, float hi) {
  unsigned r;
  asm("v_cvt_pk_bf16_f32 %0, %1, %2" : "=v"(r) : "v"(lo), "v"(hi));
  return r;
}

__device__ __forceinline__ float bf2f(unsigned short v) {
  return __uint_as_float((unsigned)v << 16);
}

// XOR-swizzled LDS index helpers (units: unsigned short elements).
__device__ __forceinline__ int swz128(int row, int col) {
  return row * 128 + (((col >> 3) ^ (row & 15)) << 3) + (col & 7);
}
__device__ __forceinline__ int swz64(int row, int col) {
  return row * 64 + (((col >> 3) ^ (row & 7)) << 3) + (col & 7);
}

// Barrier with LDS-only drain: global loads stay in flight across it.
__device__ __forceinline__ void bar() {
  asm volatile("s_waitcnt lgkmcnt(0)" ::: "memory");
  __builtin_amdgcn_s_barrier();
  asm volatile("" ::: "memory");
}

// 16-lane (DPP-row) sum via row_ror butterflies — VALU pipe, no LDS traffic.
__device__ __forceinline__ float red16(float s) {
  int t;
  t = __builtin_amdgcn_update_dpp(0, __float_as_int(s), 0x121, 0xf, 0xf, false);
  s += __int_as_float(t);
  t = __builtin_amdgcn_update_dpp(0, __float_as_int(s), 0x122, 0xf, 0xf, false);
  s += __int_as_float(t);
  t = __builtin_amdgcn_update_dpp(0, __float_as_int(s), 0x124, 0xf, 0xf, false);
  s += __int_as_float(t);
  t = __builtin_amdgcn_update_dpp(0, __float_as_int(s), 0x128, 0xf, 0xf, false);
  s += __int_as_float(t);
  return s;
}

// transpose fp32 [K][N] -> bf16 [N][K]
__global__ void wprep(const float* __restrict__ src, unsigned short* __restrict__ dst,
                      int K, int Nn) {
  int idx = blockIdx.x * 256 + threadIdx.x;
  if (idx >= K * Nn) return;
  int n = idx / K, k = idx - n * K;
  float f = src[k * Nn + n];
  unsigned u = __float_as_uint(f);
  u += 0x7fffu + ((u >> 16) & 1u);
  dst[idx] = (unsigned short)(u >> 16);
}

#define KSCL 0.36067376022224085f   // 0.25 * log2(e), folded into K epilogue

// ============================ KERNEL A =====================================
// LN1 + MERGED col-strip QKV (one A-frag read feeds V/K/Q) + wave-local
// causal attention -> AO (bf16) to global.
__global__ __launch_bounds__(512, 4)
void attn_head(const float* __restrict__ x_in, const float* __restrict__ ste,
               const float* __restrict__ g1, const float* __restrict__ b1,
               const unsigned short* __restrict__ wqt, const float* __restrict__ bq,
               const unsigned short* __restrict__ wkt, const float* __restrict__ bk,
               const unsigned short* __restrict__ wvt, const float* __restrict__ bv,
               unsigned short* __restrict__ aoG) {
  __shared__ __align__(16) unsigned short smem[32768];  // 64 KB

  const int tid = threadIdx.x;
  const int lane = tid & 63;
  const int w  = tid >> 6;         // wave 0..7
  const int lg = lane >> 4;        // 0..3
  const int li = lane & 15;
  const int hc = w * 16;           // col-strip base == head base

  const int blk = blockIdx.x;
  const int b = blk >> 9;          // N=512
  const int n = blk & 511;
  const int rs = NN * DD;
  const float* xbase = x_in + (b * TT * NN + n) * DD;
  const float* sbase = ste + (b * TT * NN + n) * DD;

  unsigned short* X2s = smem;
  unsigned short* Qb  = smem;
  unsigned short* AOb = smem + 8192;
  unsigned short* Kb  = smem + 16384;
  unsigned short* Vt  = smem + 24576;

  #define SWZ256(row, col) ((row) * 256 + ((((col) >> 3) ^ ((row) & 15)) << 3) + ((col) & 7))

  // ---------------- LN1 + STE -> X2 (all input loads hoisted) --------------
  {
    const int t0 = w * 8 + lg;
    const float* xr0 = xbase + t0 * rs + li * 8;
    const float* xr1 = xbase + (t0 + 4) * rs + li * 8;
    const float* sr0 = sbase + t0 * rs + li * 8;
    const float* sr1 = sbase + (t0 + 4) * rs + li * 8;
    float4 xA0 = *(const float4*)(xr0);
    float4 xB0 = *(const float4*)(xr0 + 4);
    float4 xA1 = *(const float4*)(xr1);
    float4 xB1 = *(const float4*)(xr1 + 4);
    float4 sA0 = *(const float4*)(sr0);
    float4 sB0 = *(const float4*)(sr0 + 4);
    float4 sA1 = *(const float4*)(sr1);
    float4 sB1 = *(const float4*)(sr1 + 4);
    float4 gA = *(const float4*)(g1 + li * 8);
    float4 gB = *(const float4*)(g1 + li * 8 + 4);
    float4 bA = *(const float4*)(b1 + li * 8);
    float4 bB = *(const float4*)(b1 + li * 8 + 4);

    {  // row t0
      float s1 = xA0.x + xA0.y + xA0.z + xA0.w + xB0.x + xB0.y + xB0.z + xB0.w;
      float s2 = xA0.x * xA0.x + xA0.y * xA0.y + xA0.z * xA0.z + xA0.w * xA0.w +
                 xB0.x * xB0.x + xB0.y * xB0.y + xB0.z * xB0.z + xB0.w * xB0.w;
      s1 = red16(s1); s2 = red16(s2);
      float mean = s1 * (1.0f / 128.0f);
      float var = fmaxf((s2 - s1 * mean) * (1.0f / 127.0f), 0.0f);  // ddof=1
      float inv = 1.0f / (sqrtf(var) + 1e-6f);
      unsigned o01 = cvtpk(gA.x * (xA0.x - mean) * inv + bA.x, gA.y * (xA0.y - mean) * inv + bA.y);
      unsigned o23 = cvtpk(gA.z * (xA0.z - mean) * inv + bA.z, gA.w * (xA0.w - mean) * inv + bA.w);
      unsigned o45 = cvtpk(gB.x * (xB0.x - mean) * inv + bB.x, gB.y * (xB0.y - mean) * inv + bB.y);
      unsigned o67 = cvtpk(gB.z * (xB0.z - mean) * inv + bB.z, gB.w * (xB0.w - mean) * inv + bB.w);
      *(uint4*)(X2s + SWZ256(t0, li * 8)) = (uint4){o01, o23, o45, o67};
    }
    {  // row t0+4
      float s1 = xA1.x + xA1.y + xA1.z + xA1.w + xB1.x + xB1.y + xB1.z + xB1.w;
      float s2 = xA1.x * xA1.x + xA1.y * xA1.y + xA1.z * xA1.z + xA1.w * xA1.w +
                 xB1.x * xB1.x + xB1.y * xB1.y + xB1.z * xB1.z + xB1.w * xB1.w;
      s1 = red16(s1); s2 = red16(s2);
      float mean = s1 * (1.0f / 128.0f);
      float var = fmaxf((s2 - s1 * mean) * (1.0f / 127.0f), 0.0f);
      float inv = 1.0f / (sqrtf(var) + 1e-6f);
      unsigned o01 = cvtpk(gA.x * (xA1.x - mean) * inv + bA.x, gA.y * (xA1.y - mean) * inv + bA.y);
      unsigned o23 = cvtpk(gA.z * (xA1.z - mean) * inv + bA.z, gA.w * (xA1.w - mean) * inv + bA.w);
      unsigned o45 = cvtpk(gB.x * (xB1.x - mean) * inv + bB.x, gB.y * (xB1.y - mean) * inv + bB.y);
      unsigned o67 = cvtpk(gB.z * (xB1.z - mean) * inv + bB.z, gB.w * (xB1.w - mean) * inv + bB.w);
      *(uint4*)(X2s + SWZ256(t0 + 4, li * 8)) = (uint4){o01, o23, o45, o67};
    }
    *(uint4*)(X2s + SWZ256(t0, 128 + li * 8)) =
        (uint4){cvtpk(sA0.x, sA0.y), cvtpk(sA0.z, sA0.w), cvtpk(sB0.x, sB0.y), cvtpk(sB0.z, sB0.w)};
    *(uint4*)(X2s + SWZ256(t0 + 4, 128 + li * 8)) =
        (uint4){cvtpk(sA1.x, sA1.y), cvtpk(sA1.z, sA1.w), cvtpk(sB1.x, sB1.y), cvtpk(sB1.z, sB1.w)};
  }

  bar();  // B0: X2 visible

  // ---------- MERGED V/K/Q col-strip GEMMs (one A-read, three MFMAs) -------
  f32x4 va[4], ka[4], qa[4];
  #pragma unroll
  for (int rg = 0; rg < 4; ++rg) {
    va[rg] = (f32x4){0, 0, 0, 0};
    ka[rg] = (f32x4){0, 0, 0, 0};
    qa[rg] = (f32x4){0, 0, 0, 0};
  }
  {
    const unsigned short* vB = wvt + hc * 256;
    const unsigned short* kB = wkt + hc * 256;
    const unsigned short* qB = wqt + hc * 256;
    #pragma unroll
    for (int kk = 0; kk < 8; ++kk) {
      bf16x8 bv_ = *(const bf16x8*)(vB + li * 256 + kk * 32 + lg * 8);
      bf16x8 bk_ = *(const bf16x8*)(kB + li * 256 + kk * 32 + lg * 8);
      bf16x8 bq_ = *(const bf16x8*)(qB + li * 256 + kk * 32 + lg * 8);
      #pragma unroll
      for (int rg = 0; rg < 4; ++rg) {
        bf16x8 af = *(const bf16x8*)(X2s + SWZ256(rg * 16 + li, kk * 32 + lg * 8));
        va[rg] = __builtin_amdgcn_mfma_f32_16x16x32_bf16(af, bv_, va[rg], 0, 0, 0);
        ka[rg] = __builtin_amdgcn_mfma_f32_16x16x32_bf16(af, bk_, ka[rg], 0, 0, 0);
        qa[rg] = __builtin_amdgcn_mfma_f32_16x16x32_bf16(af, bq_, qa[rg], 0, 0, 0);
      }
    }
  }

  // V epilogue -> Vt (non-overlay region; pre-B0e is safe)
  {
    float bvv = bv[hc + li];
    int d = hc + li;
    #pragma unroll
    for (int rg = 0; rg < 4; ++rg) {
      float v0 = fmaxf(va[rg][0] + bvv, 0.0f);
      float v1 = fmaxf(va[rg][1] + bvv, 0.0f);
      float v2 = fmaxf(va[rg][2] + bvv, 0.0f);
      float v3 = fmaxf(va[rg][3] + bvv, 0.0f);
      uint2 pv; pv.x = cvtpk(v0, v1); pv.y = cvtpk(v2, v3);
      *(uint2*)(Vt + swz64(d, rg * 16 + lg * 4)) = pv;
    }
  }
  // K epilogue (scaled) -> Kb (non-overlay region)
  {
    float bkv = bk[hc + li];
    int col = hc + li;
    #pragma unroll
    for (int rg = 0; rg < 4; ++rg) {
      float k0 = fmaxf(ka[rg][0] + bkv, 0.0f) * KSCL;
      float k1 = fmaxf(ka[rg][1] + bkv, 0.0f) * KSCL;
      float k2 = fmaxf(ka[rg][2] + bkv, 0.0f) * KSCL;
      float k3 = fmaxf(ka[rg][3] + bkv, 0.0f) * KSCL;
      unsigned p01 = cvtpk(k0, k1), p23 = cvtpk(k2, k3);
      Kb[swz128(rg * 16 + lg * 4 + 0, col)] = (unsigned short)p01;
      Kb[swz128(rg * 16 + lg * 4 + 1, col)] = (unsigned short)(p01 >> 16);
      Kb[swz128(rg * 16 + lg * 4 + 2, col)] = (unsigned short)p23;
      Kb[swz128(rg * 16 + lg * 4 + 3, col)] = (unsigned short)(p23 >> 16);
    }
  }

  bar();  // B0e: ALL X2 reads done -> Qb/AOb overlays live

  // Q epilogue -> Qb (own col strip; consumed only by this wave)
  {
    float bqv = bq[hc + li];
    int col = hc + li;
    #pragma unroll
    for (int rg = 0; rg < 4; ++rg) {
      float v0 = fmaxf(qa[rg][0] + bqv, 0.0f);
      float v1 = fmaxf(qa[rg][1] + bqv, 0.0f);
      float v2 = fmaxf(qa[rg][2] + bqv, 0.0f);
      float v3 = fmaxf(qa[rg][3] + bqv, 0.0f);
      unsigned p01 = cvtpk(v0, v1), p23 = cvtpk(v2, v3);
      Qb[swz128(rg * 16 + lg * 4 + 0, col)] = (unsigned short)p01;
      Qb[swz128(rg * 16 + lg * 4 + 1, col)] = (unsigned short)(p01 >> 16);
      Qb[swz128(rg * 16 + lg * 4 + 2, col)] = (unsigned short)p23;
      Qb[swz128(rg * 16 + lg * 4 + 3, col)] = (unsigned short)(p23 >> 16);
    }
  }

  // ---------------- causal attention, head w (all strips wave-local) -------
  {
    const bf16x8 zf = (bf16x8){0, 0, 0, 0, 0, 0, 0, 0};
    bf16x8 kf[4], vf[2];
    #pragma unroll
    for (int pt = 0; pt < 4; ++pt)
      kf[pt] = (lg < 2) ? *(const bf16x8*)(Kb + swz128(pt * 16 + li, hc + lg * 8)) : zf;
    #pragma unroll
    for (int ks = 0; ks < 2; ++ks)
      vf[ks] = *(const bf16x8*)(Vt + swz64(hc + li, ks * 32 + lg * 8));

    #pragma unroll
    for (int qt = 0; qt < 4; ++qt) {
      bf16x8 qf = (lg < 2) ? *(const bf16x8*)(Qb + swz128(qt * 16 + li, hc + lg * 8)) : zf;
      f32x4 st[4];
      #pragma unroll
      for (int pt = 0; pt < 4; ++pt)
        if (pt <= qt)
          st[pt] = __builtin_amdgcn_mfma_f32_16x16x32_bf16(kf[pt], qf, (f32x4){0, 0, 0, 0}, 0, 0, 0);

      float ssum = 0.0f;
      unsigned pa[4], pb[4];
      #pragma unroll
      for (int pt = 0; pt < 4; ++pt) {
        if (pt > qt) { pa[pt] = 0; pb[pt] = 0; continue; }
        float e0 = exp2f(st[pt][0]);
        float e1 = exp2f(st[pt][1]);
        float e2 = exp2f(st[pt][2]);
        float e3 = exp2f(st[pt][3]);
        if (pt == qt) {  // diagonal tile: mask p_local > q_local
          e0 = (4 * lg + 0 > li) ? 0.0f : e0;
          e1 = (4 * lg + 1 > li) ? 0.0f : e1;
          e2 = (4 * lg + 2 > li) ? 0.0f : e2;
          e3 = (4 * lg + 3 > li) ? 0.0f : e3;
        }
        ssum += e0 + e1 + e2 + e3;
        pa[pt] = cvtpk(e0, e1);
        pb[pt] = cvtpk(e2, e3);
      }
      ssum += __shfl_xor(ssum, 16, 64);
      ssum += __shfl_xor(ssum, 32, 64);
      float rinv = 1.0f / ssum;

      f32x4 oa = (f32x4){0, 0, 0, 0};
      #pragma unroll
      for (int ks = 0; ks < 2; ++ks) {
        if (ks * 2 > qt) continue;
        unsigned x = pa[2 * ks], y = pa[2 * ks + 1];
        asm("v_permlane32_swap_b32 %0, %1" : "+v"(x), "+v"(y));
        asm("v_permlane16_swap_b32 %0, %1" : "+v"(x), "+v"(y));
        unsigned u2 = pb[2 * ks], v2 = pb[2 * ks + 1];
        asm("v_permlane32_swap_b32 %0, %1" : "+v"(u2), "+v"(v2));
        asm("v_permlane16_swap_b32 %0, %1" : "+v"(u2), "+v"(v2));
        union { unsigned uw[4]; bf16x8 h; } pu;
        pu.uw[0] = x; pu.uw[1] = u2; pu.uw[2] = y; pu.uw[3] = v2;
        oa = __builtin_amdgcn_mfma_f32_16x16x32_bf16(vf[ks], pu.h, oa, 0, 0, 0);
      }
      uint2 ov;
      ov.x = cvtpk(oa[0] * rinv, oa[1] * rinv);
      ov.y = cvtpk(oa[2] * rinv, oa[3] * rinv);
      *(uint2*)(AOb + swz128(qt * 16 + li, hc + lg * 4)) = ov;
    }
  }

  bar();  // B2: AO strips visible

  // Coalesced AO store: wave w -> rows w*8..w*8+7, 16 lanes x 16B per row
  #pragma unroll
  for (int pass = 0; pass < 2; ++pass) {
    int t = w * 8 + pass * 4 + lg;
    uint4 v = *(const uint4*)(AOb + swz128(t, li * 8));
    *(uint4*)(aoG + ((b * TT + t) * NN + n) * DD + li * 8) = v;
  }
  #undef SWZ256
}

// ============================ KERNEL B =====================================
// Tail in the head's image (R21-verified: tail ~100 us): 8-wave blocks over
// 64 flat rows, col-strip GEMMs, acc = 16 regs, 48KB LDS, 5 lgkm-barriers.
__global__ __launch_bounds__(512)
void tail_ffn(const unsigned short* __restrict__ aoG, const float* __restrict__ x_in,
              const float* __restrict__ g2, const float* __restrict__ b2,
              const unsigned short* __restrict__ wo1t, const float* __restrict__ bo1,
              const unsigned short* __restrict__ wo2t, const float* __restrict__ bo2,
              const unsigned short* __restrict__ wf1t, const float* __restrict__ bf1,
              const unsigned short* __restrict__ wf2t, const float* __restrict__ bf2,
              float* __restrict__ out) {
  __shared__ __align__(16) unsigned short smem[24576];  // 48 KB
  const int tid = threadIdx.x;
  const int lane = tid & 63;
  const int w  = tid >> 6;          // wave 0..7
  const int lg = lane >> 4;
  const int li = lane & 15;
  const int hc = w * 16;            // col strip for GEMM passes
  const int R0 = blockIdx.x * 64;   // flat row base (B*T*N rows total)

  unsigned short* Ar = smem;            // AO, later Xn2
  unsigned short* Br = smem + 8192;     // H1, later Hf
  unsigned short* Cr = smem + 16384;    // x2 (bf16; persists)

  // ---- stage AO[64][128] -> Ar (coalesced; wave w rows w*8..w*8+7) --------
  #pragma unroll
  for (int p = 0; p < 2; ++p) {
    int t = w * 8 + p * 4 + lg;
    uint4 v = *(const uint4*)(aoG + (R0 + t) * DD + li * 8);
    *(uint4*)(Ar + swz128(t, li * 8)) = v;
  }
  bar();  // AO visible

  // ---- O1 col-strip: H1[0:64][hc:hc+16] -> Br -----------------------------
  {
    f32x4 acc[4];
    #pragma unroll
    for (int i = 0; i < 4; ++i) acc[i] = (f32x4){0, 0, 0, 0};
    #pragma unroll
    for (int kk = 0; kk < 4; ++kk) {
      bf16x8 bc = *(const bf16x8*)(wo1t + (hc + li) * 128 + kk * 32 + lg * 8);
      #pragma unroll
      for (int rg = 0; rg < 4; ++rg) {
        bf16x8 af = *(const bf16x8*)(Ar + swz128(rg * 16 + li, kk * 32 + lg * 8));
        acc[rg] = __builtin_amdgcn_mfma_f32_16x16x32_bf16(af, bc, acc[rg], 0, 0, 0);
      }
    }
    float bvv = bo1[hc + li];
    int col = hc + li;
    #pragma unroll
    for (int rg = 0; rg < 4; ++rg) {
      unsigned p01 = cvtpk(fmaxf(acc[rg][0] + bvv, 0.0f), fmaxf(acc[rg][1] + bvv, 0.0f));
      unsigned p23 = cvtpk(fmaxf(acc[rg][2] + bvv, 0.0f), fmaxf(acc[rg][3] + bvv, 0.0f));
      Br[swz128(rg * 16 + lg * 4 + 0, col)] = (unsigned short)p01;
      Br[swz128(rg * 16 + lg * 4 + 1, col)] = (unsigned short)(p01 >> 16);
      Br[swz128(rg * 16 + lg * 4 + 2, col)] = (unsigned short)p23;
      Br[swz128(rg * 16 + lg * 4 + 3, col)] = (unsigned short)(p23 >> 16);
    }
  }
  bar();  // H1 visible; Ar reads done

  // ---- O2 col-strip + residual: x2 -> Cr ----------------------------------
  {
    f32x4 acc[4];
    #pragma unroll
    for (int i = 0; i < 4; ++i) acc[i] = (f32x4){0, 0, 0, 0};
    #pragma unroll
    for (int kk = 0; kk < 4; ++kk) {
      bf16x8 bc = *(const bf16x8*)(wo2t + (hc + li) * 128 + kk * 32 + lg * 8);
      #pragma unroll
      for (int rg = 0; rg < 4; ++rg) {
        bf16x8 af = *(const bf16x8*)(Br + swz128(rg * 16 + li, kk * 32 + lg * 8));
        acc[rg] = __builtin_amdgcn_mfma_f32_16x16x32_bf16(af, bc, acc[rg], 0, 0, 0);
      }
    }
    float bvv = bo2[hc + li];
    int col = hc + li;
    #pragma unroll
    for (int rg = 0; rg < 4; ++rg) {
      float x0 = x_in[(R0 + rg * 16 + lg * 4 + 0) * DD + col];
      float x1 = x_in[(R0 + rg * 16 + lg * 4 + 1) * DD + col];
      float x2v = x_in[(R0 + rg * 16 + lg * 4 + 2) * DD + col];
      float x3 = x_in[(R0 + rg * 16 + lg * 4 + 3) * DD + col];
      unsigned p01 = cvtpk(acc[rg][0] + bvv + x0, acc[rg][1] + bvv + x1);
      unsigned p23 = cvtpk(acc[rg][2] + bvv + x2v, acc[rg][3] + bvv + x3);
      Cr[swz128(rg * 16 + lg * 4 + 0, col)] = (unsigned short)p01;
      Cr[swz128(rg * 16 + lg * 4 + 1, col)] = (unsigned short)(p01 >> 16);
      Cr[swz128(rg * 16 + lg * 4 + 2, col)] = (unsigned short)p23;
      Cr[swz128(rg * 16 + lg * 4 + 3, col)] = (unsigned short)(p23 >> 16);
    }
  }
  bar();  // x2 visible

  // ---- LN2 (wave w re-reads rows w*8..w*8+7 full-width) -------------------
  {
    float4 gA = *(const float4*)(g2 + li * 8);
    float4 gB = *(const float4*)(g2 + li * 8 + 4);
    float4 bA = *(const float4*)(b2 + li * 8);
    float4 bB = *(const float4*)(b2 + li * 8 + 4);
    #pragma unroll
    for (int p = 0; p < 2; ++p) {
      int t = w * 8 + p * 4 + lg;
      uint4 v = *(const uint4*)(Cr + swz128(t, li * 8));
      float f0 = bf2f((unsigned short)v.x),  f1 = bf2f((unsigned short)(v.x >> 16));
      float f2v = bf2f((unsigned short)v.y), f3 = bf2f((unsigned short)(v.y >> 16));
      float f4 = bf2f((unsigned short)v.z),  f5 = bf2f((unsigned short)(v.z >> 16));
      float f6 = bf2f((unsigned short)v.w),  f7 = bf2f((unsigned short)(v.w >> 16));
      float s1 = f0 + f1 + f2v + f3 + f4 + f5 + f6 + f7;
      float s2 = f0 * f0 + f1 * f1 + f2v * f2v + f3 * f3 + f4 * f4 + f5 * f5 + f6 * f6 + f7 * f7;
      s1 = red16(s1); s2 = red16(s2);
      float mean = s1 * (1.0f / 128.0f);
      float var = fmaxf((s2 - s1 * mean) * (1.0f / 127.0f), 0.0f);  // ddof=1
      float iv = 1.0f / (sqrtf(var) + 1e-6f);
      unsigned o01 = cvtpk(gA.x * (f0 - mean) * iv + bA.x, gA.y * (f1 - mean) * iv + bA.y);
      unsigned o23 = cvtpk(gA.z * (f2v - mean) * iv + bA.z, gA.w * (f3 - mean) * iv + bA.w);
      unsigned o45 = cvtpk(gB.x * (f4 - mean) * iv + bB.x, gB.y * (f5 - mean) * iv + bB.y);
      unsigned o67 = cvtpk(gB.z * (f6 - mean) * iv + bB.z, gB.w * (f7 - mean) * iv + bB.w);
      *(uint4*)(Ar + swz128(t, li * 8)) = (uint4){o01, o23, o45, o67};  // Xn2
    }
  }
  bar();  // Xn2 visible

  // ---- F1 col-strip: Hf -> Br ---------------------------------------------
  {
    f32x4 acc[4];
    #pragma unroll
    for (int i = 0; i < 4; ++i) acc[i] = (f32x4){0, 0, 0, 0};
    #pragma unroll
    for (int kk = 0; kk < 4; ++kk) {
      bf16x8 bc = *(const bf16x8*)(wf1t + (hc + li) * 128 + kk * 32 + lg * 8);
      #pragma unroll
      for (int rg = 0; rg < 4; ++rg) {
        bf16x8 af = *(const bf16x8*)(Ar + swz128(rg * 16 + li, kk * 32 + lg * 8));
        acc[rg] = __builtin_amdgcn_mfma_f32_16x16x32_bf16(af, bc, acc[rg], 0, 0, 0);
      }
    }
    float bvv = bf1[hc + li];
    int col = hc + li;
    #pragma unroll
    for (int rg = 0; rg < 4; ++rg) {
      unsigned p01 = cvtpk(fmaxf(acc[rg][0] + bvv, 0.0f), fmaxf(acc[rg][1] + bvv, 0.0f));
      unsigned p23 = cvtpk(fmaxf(acc[rg][2] + bvv, 0.0f), fmaxf(acc[rg][3] + bvv, 0.0f));
      Br[swz128(rg * 16 + lg * 4 + 0, col)] = (unsigned short)p01;
      Br[swz128(rg * 16 + lg * 4 + 1, col)] = (unsigned short)(p01 >> 16);
      Br[swz128(rg * 16 + lg * 4 + 2, col)] = (unsigned short)p23;
      Br[swz128(rg * 16 + lg * 4 + 3, col)] = (unsigned short)(p23 >> 16);
    }
  }
  bar();  // Hf visible

  // ---- F2 col-strip + final residual (x2 from Cr) -> out ------------------
  {
    f32x4 acc[4];
    #pragma unroll
    for (int i = 0; i < 4; ++i) acc[i] = (f32x4){0, 0, 0, 0};
    #pragma unroll
    for (int kk = 0; kk < 4; ++kk) {
      bf16x8 bc = *(const bf16x8*)(wf2t + (hc + li) * 128 + kk * 32 + lg * 8);
      #pragma unroll
      for (int rg = 0; rg < 4; ++rg) {
        bf16x8 af = *(const bf16x8*)(Br + swz128(rg * 16 + li, kk * 32 + lg * 8));
        acc[rg] = __builtin_amdgcn_mfma_f32_16x16x32_bf16(af, bc, acc[rg], 0, 0, 0);
      }
    }
    float bvv = bf2[hc + li];
    int col = hc + li;
    #pragma unroll
    for (int rg = 0; rg < 4; ++rg) {
      #pragma unroll
      for (int r = 0; r < 4; ++r) {
        int row = rg * 16 + lg * 4 + r;
        float x2v = bf2f(Cr[swz128(row, col)]);
        out[(R0 + row) * DD + col] = x2v + fmaxf(acc[rg][r] + bvv, 0.0f);
      }
    }
  }
}

extern "C" void kernel_launch(void* const* d_in, const int* in_sizes, int n_in,
                              void* d_out, int out_size, void* d_ws, size_t ws_size,
                              hipStream_t stream) {
  const float* x   = (const float*)d_in[0];
  const float* ste = (const float*)d_in[1];
  const float* g1 = (const float*)d_in[3];
  const float* b1 = (const float*)d_in[4];
  const float* g2 = (const float*)d_in[5];
  const float* b2 = (const float*)d_in[6];
  const float* Wq = (const float*)d_in[7];   const float* bq  = (const float*)d_in[8];
  const float* Wk = (const float*)d_in[9];   const float* bk  = (const float*)d_in[10];
  const float* Wv = (const float*)d_in[11];  const float* bv  = (const float*)d_in[12];
  const float* Wo1 = (const float*)d_in[13]; const float* bo1 = (const float*)d_in[14];
  const float* Wo2 = (const float*)d_in[15]; const float* bo2 = (const float*)d_in[16];
  const float* Wf1 = (const float*)d_in[17]; const float* bf1 = (const float*)d_in[18];
  const float* Wf2 = (const float*)d_in[19]; const float* bf2 = (const float*)d_in[20];
  float* out = (float*)d_out;

  unsigned short* wsu = (unsigned short*)d_ws;
  unsigned short* wq_t  = wsu;             // [128][256]
  unsigned short* wk_t  = wsu + 32768;
  unsigned short* wv_t  = wsu + 65536;
  unsigned short* wo1_t = wsu + 98304;     // [128][128]
  unsigned short* wo2_t = wsu + 114688;
  unsigned short* wf1_t = wsu + 131072;
  unsigned short* wf2_t = wsu + 147456;
  unsigned short* ao    = wsu + 163840;    // [B*T*N][128] bf16 = 64 MB

  hipLaunchKernelGGL(wprep, dim3(128), dim3(256), 0, stream, Wq, wq_t, 256, 128);
  hipLaunchKernelGGL(wprep, dim3(128), dim3(256), 0, stream, Wk, wk_t, 256, 128);
  hipLaunchKernelGGL(wprep, dim3(128), dim3(256), 0, stream, Wv, wv_t, 256, 128);
  hipLaunchKernelGGL(wprep, dim3(64), dim3(256), 0, stream, Wo1, wo1_t, 128, 128);
  hipLaunchKernelGGL(wprep, dim3(64), dim3(256), 0, stream, Wo2, wo2_t, 128, 128);
  hipLaunchKernelGGL(wprep, dim3(64), dim3(256), 0, stream, Wf1, wf1_t, 128, 128);
  hipLaunchKernelGGL(wprep, dim3(64), dim3(256), 0, stream, Wf2, wf2_t, 128, 128);

  hipLaunchKernelGGL(attn_head, dim3(8 * NN), dim3(512), 0, stream,
                     x, ste, g1, b1, wq_t, bq, wk_t, bk, wv_t, bv, ao);
  hipLaunchKernelGGL(tail_ffn, dim3(8 * TT * NN / 64), dim3(512), 0, stream,
                     ao, x, g2, b2, wo1_t, bo1, wo2_t, bo2,
                     wf1_t, bf1, wf2_t, bf2, out);
}

// Round 23
// 249.310 us; speedup vs baseline: 1.9062x; 1.1257x over previous
//
#include <hip/hip_runtime.h>

#define TT 64
#define NN 512
#define DD 128

typedef __attribute__((ext_vector_type(8))) short bf16x8;
typedef __attribute__((ext_vector_type(4))) float f32x4;

__device__ __forceinline__ unsigned cvtpk(float lo, float hi) {
  unsigned r;
  asm("v_cvt_pk_bf16_f32 %0, %1, %2" : "=v"(r) : "v"(lo), "v"(hi));
  return r;
}

__device__ __forceinline__ float bf2f(unsigned short v) {
  return __uint_as_float((unsigned)v << 16);
}

// XOR-swizzled LDS index helpers (units: unsigned short elements).
__device__ __forceinline__ int swz128(int row, int col) {
  return row * 128 + (((col >> 3) ^ (row & 15)) << 3) + (col & 7);
}
__device__ __forceinline__ int swz64(int row, int col) {
  return row * 64 + (((col >> 3) ^ (row & 7)) << 3) + (col & 7);
}

// Barrier with LDS-only drain: global loads stay in flight across it.
__device__ __forceinline__ void bar() {
  asm volatile("s_waitcnt lgkmcnt(0)" ::: "memory");
  __builtin_amdgcn_s_barrier();
  asm volatile("" ::: "memory");
}

// 16-lane (DPP-row) sum via row_ror butterflies — VALU pipe, no LDS traffic.
__device__ __forceinline__ float red16(float s) {
  int t;
  t = __builtin_amdgcn_update_dpp(0, __float_as_int(s), 0x121, 0xf, 0xf, false);
  s += __int_as_float(t);
  t = __builtin_amdgcn_update_dpp(0, __float_as_int(s), 0x122, 0xf, 0xf, false);
  s += __int_as_float(t);
  t = __builtin_amdgcn_update_dpp(0, __float_as_int(s), 0x124, 0xf, 0xf, false);
  s += __int_as_float(t);
  t = __builtin_amdgcn_update_dpp(0, __float_as_int(s), 0x128, 0xf, 0xf, false);
  s += __int_as_float(t);
  return s;
}

// transpose fp32 [K][N] -> bf16 [N][K]
__global__ void wprep(const float* __restrict__ src, unsigned short* __restrict__ dst,
                      int K, int Nn) {
  int idx = blockIdx.x * 256 + threadIdx.x;
  if (idx >= K * Nn) return;
  int n = idx / K, k = idx - n * K;
  float f = src[k * Nn + n];
  unsigned u = __float_as_uint(f);
  u += 0x7fffu + ((u >> 16) & 1u);
  dst[idx] = (unsigned short)(u >> 16);
}

#define KSCL 0.36067376022224085f   // 0.25 * log2(e), folded into K epilogue

// ====================== FUSED LAYER (head + tail) ==========================
// Per block: (b,n), 64 time-rows. Head: LN1 -> merged col-strip QKV ->
// wave-local causal attention (AO stays in LDS). Tail: col-strip O1/O2 ->
// residual/LN2 -> col-strip F1/F2 -> out. All phases low-VGPR col-strip
// (R21/R22-verified shapes); 8 lgkm barriers; 64KB LDS; 2 blocks/CU overlap.
__global__ __launch_bounds__(512, 4)
void fused_layer(const float* __restrict__ x_in, const float* __restrict__ ste,
                 const float* __restrict__ g1, const float* __restrict__ b1,
                 const float* __restrict__ g2, const float* __restrict__ b2,
                 const unsigned short* __restrict__ wqt, const float* __restrict__ bq,
                 const unsigned short* __restrict__ wkt, const float* __restrict__ bk,
                 const unsigned short* __restrict__ wvt, const float* __restrict__ bv,
                 const unsigned short* __restrict__ wo1t, const float* __restrict__ bo1,
                 const unsigned short* __restrict__ wo2t, const float* __restrict__ bo2,
                 const unsigned short* __restrict__ wf1t, const float* __restrict__ bf1,
                 const unsigned short* __restrict__ wf2t, const float* __restrict__ bf2,
                 float* __restrict__ out) {
  __shared__ __align__(16) unsigned short smem[32768];  // 64 KB

  const int tid = threadIdx.x;
  const int lane = tid & 63;
  const int w  = tid >> 6;         // wave 0..7
  const int lg = lane >> 4;        // 0..3
  const int li = lane & 15;
  const int hc = w * 16;           // col strip == head base

  const int blk = blockIdx.x;
  const int b = blk >> 9;          // N=512
  const int n = blk & 511;
  const int rs = NN * DD;
  const float* xbase = x_in + (b * TT * NN + n) * DD;
  const float* sbase = ste + (b * TT * NN + n) * DD;

  // Region plan:
  //  [0,16384)      X2s [64][256]; post-B0e lower half = Qb; post-B4 = Xn2 (Ar)
  //  [8192,16384)   AOb (attention out) — overlay on X2 upper after B0e
  //  [16384,24576)  Kb; post-B2 = Br (H1, then Hf)
  //  [24576,32768)  Vt; post-B3 = Cr (x2 bf16, persists to final residual)
  unsigned short* X2s = smem;
  unsigned short* Qb  = smem;
  unsigned short* Ar  = smem;
  unsigned short* AOb = smem + 8192;
  unsigned short* Kb  = smem + 16384;
  unsigned short* Br  = smem + 16384;
  unsigned short* Vt  = smem + 24576;
  unsigned short* Cr  = smem + 24576;

  #define SWZ256(row, col) ((row) * 256 + ((((col) >> 3) ^ ((row) & 15)) << 3) + ((col) & 7))

  // ---------------- LN1 + STE -> X2 (all input loads hoisted) --------------
  {
    const int t0 = w * 8 + lg;
    const float* xr0 = xbase + t0 * rs + li * 8;
    const float* xr1 = xbase + (t0 + 4) * rs + li * 8;
    const float* sr0 = sbase + t0 * rs + li * 8;
    const float* sr1 = sbase + (t0 + 4) * rs + li * 8;
    float4 xA0 = *(const float4*)(xr0);
    float4 xB0 = *(const float4*)(xr0 + 4);
    float4 xA1 = *(const float4*)(xr1);
    float4 xB1 = *(const float4*)(xr1 + 4);
    float4 sA0 = *(const float4*)(sr0);
    float4 sB0 = *(const float4*)(sr0 + 4);
    float4 sA1 = *(const float4*)(sr1);
    float4 sB1 = *(const float4*)(sr1 + 4);
    float4 gA = *(const float4*)(g1 + li * 8);
    float4 gB = *(const float4*)(g1 + li * 8 + 4);
    float4 bA = *(const float4*)(b1 + li * 8);
    float4 bB = *(const float4*)(b1 + li * 8 + 4);

    {  // row t0
      float s1 = xA0.x + xA0.y + xA0.z + xA0.w + xB0.x + xB0.y + xB0.z + xB0.w;
      float s2 = xA0.x * xA0.x + xA0.y * xA0.y + xA0.z * xA0.z + xA0.w * xA0.w +
                 xB0.x * xB0.x + xB0.y * xB0.y + xB0.z * xB0.z + xB0.w * xB0.w;
      s1 = red16(s1); s2 = red16(s2);
      float mean = s1 * (1.0f / 128.0f);
      float var = fmaxf((s2 - s1 * mean) * (1.0f / 127.0f), 0.0f);  // ddof=1
      float inv = 1.0f / (sqrtf(var) + 1e-6f);
      unsigned o01 = cvtpk(gA.x * (xA0.x - mean) * inv + bA.x, gA.y * (xA0.y - mean) * inv + bA.y);
      unsigned o23 = cvtpk(gA.z * (xA0.z - mean) * inv + bA.z, gA.w * (xA0.w - mean) * inv + bA.w);
      unsigned o45 = cvtpk(gB.x * (xB0.x - mean) * inv + bB.x, gB.y * (xB0.y - mean) * inv + bB.y);
      unsigned o67 = cvtpk(gB.z * (xB0.z - mean) * inv + bB.z, gB.w * (xB0.w - mean) * inv + bB.w);
      *(uint4*)(X2s + SWZ256(t0, li * 8)) = (uint4){o01, o23, o45, o67};
    }
    {  // row t0+4
      float s1 = xA1.x + xA1.y + xA1.z + xA1.w + xB1.x + xB1.y + xB1.z + xB1.w;
      float s2 = xA1.x * xA1.x + xA1.y * xA1.y + xA1.z * xA1.z + xA1.w * xA1.w +
                 xB1.x * xB1.x + xB1.y * xB1.y + xB1.z * xB1.z + xB1.w * xB1.w;
      s1 = red16(s1); s2 = red16(s2);
      float mean = s1 * (1.0f / 128.0f);
      float var = fmaxf((s2 - s1 * mean) * (1.0f / 127.0f), 0.0f);
      float inv = 1.0f / (sqrtf(var) + 1e-6f);
      unsigned o01 = cvtpk(gA.x * (xA1.x - mean) * inv + bA.x, gA.y * (xA1.y - mean) * inv + bA.y);
      unsigned o23 = cvtpk(gA.z * (xA1.z - mean) * inv + bA.z, gA.w * (xA1.w - mean) * inv + bA.w);
      unsigned o45 = cvtpk(gB.x * (xB1.x - mean) * inv + bB.x, gB.y * (xB1.y - mean) * inv + bB.y);
      unsigned o67 = cvtpk(gB.z * (xB1.z - mean) * inv + bB.z, gB.w * (xB1.w - mean) * inv + bB.w);
      *(uint4*)(X2s + SWZ256(t0 + 4, li * 8)) = (uint4){o01, o23, o45, o67};
    }
    *(uint4*)(X2s + SWZ256(t0, 128 + li * 8)) =
        (uint4){cvtpk(sA0.x, sA0.y), cvtpk(sA0.z, sA0.w), cvtpk(sB0.x, sB0.y), cvtpk(sB0.z, sB0.w)};
    *(uint4*)(X2s + SWZ256(t0 + 4, 128 + li * 8)) =
        (uint4){cvtpk(sA1.x, sA1.y), cvtpk(sA1.z, sA1.w), cvtpk(sB1.x, sB1.y), cvtpk(sB1.z, sB1.w)};
  }

  bar();  // B0: X2 visible

  // ---------- MERGED V/K/Q col-strip GEMMs (one A-read, three MFMAs) -------
  f32x4 va[4], ka[4], qa[4];
  #pragma unroll
  for (int rg = 0; rg < 4; ++rg) {
    va[rg] = (f32x4){0, 0, 0, 0};
    ka[rg] = (f32x4){0, 0, 0, 0};
    qa[rg] = (f32x4){0, 0, 0, 0};
  }
  {
    const unsigned short* vB = wvt + hc * 256;
    const unsigned short* kB = wkt + hc * 256;
    const unsigned short* qB = wqt + hc * 256;
    #pragma unroll
    for (int kk = 0; kk < 8; ++kk) {
      bf16x8 bv_ = *(const bf16x8*)(vB + li * 256 + kk * 32 + lg * 8);
      bf16x8 bk_ = *(const bf16x8*)(kB + li * 256 + kk * 32 + lg * 8);
      bf16x8 bq_ = *(const bf16x8*)(qB + li * 256 + kk * 32 + lg * 8);
      #pragma unroll
      for (int rg = 0; rg < 4; ++rg) {
        bf16x8 af = *(const bf16x8*)(X2s + SWZ256(rg * 16 + li, kk * 32 + lg * 8));
        va[rg] = __builtin_amdgcn_mfma_f32_16x16x32_bf16(af, bv_, va[rg], 0, 0, 0);
        ka[rg] = __builtin_amdgcn_mfma_f32_16x16x32_bf16(af, bk_, ka[rg], 0, 0, 0);
        qa[rg] = __builtin_amdgcn_mfma_f32_16x16x32_bf16(af, bq_, qa[rg], 0, 0, 0);
      }
    }
  }

  // V epilogue -> Vt (non-overlay until B3)
  {
    float bvv = bv[hc + li];
    int d = hc + li;
    #pragma unroll
    for (int rg = 0; rg < 4; ++rg) {
      float v0 = fmaxf(va[rg][0] + bvv, 0.0f);
      float v1 = fmaxf(va[rg][1] + bvv, 0.0f);
      float v2 = fmaxf(va[rg][2] + bvv, 0.0f);
      float v3 = fmaxf(va[rg][3] + bvv, 0.0f);
      uint2 pv; pv.x = cvtpk(v0, v1); pv.y = cvtpk(v2, v3);
      *(uint2*)(Vt + swz64(d, rg * 16 + lg * 4)) = pv;
    }
  }
  // K epilogue (scaled) -> Kb
  {
    float bkv = bk[hc + li];
    int col = hc + li;
    #pragma unroll
    for (int rg = 0; rg < 4; ++rg) {
      float k0 = fmaxf(ka[rg][0] + bkv, 0.0f) * KSCL;
      float k1 = fmaxf(ka[rg][1] + bkv, 0.0f) * KSCL;
      float k2 = fmaxf(ka[rg][2] + bkv, 0.0f) * KSCL;
      float k3 = fmaxf(ka[rg][3] + bkv, 0.0f) * KSCL;
      unsigned p01 = cvtpk(k0, k1), p23 = cvtpk(k2, k3);
      Kb[swz128(rg * 16 + lg * 4 + 0, col)] = (unsigned short)p01;
      Kb[swz128(rg * 16 + lg * 4 + 1, col)] = (unsigned short)(p01 >> 16);
      Kb[swz128(rg * 16 + lg * 4 + 2, col)] = (unsigned short)p23;
      Kb[swz128(rg * 16 + lg * 4 + 3, col)] = (unsigned short)(p23 >> 16);
    }
  }

  bar();  // B0e: ALL X2 reads done -> Qb/AOb overlays live

  // Q epilogue -> Qb (own col strip; consumed only by this wave)
  {
    float bqv = bq[hc + li];
    int col = hc + li;
    #pragma unroll
    for (int rg = 0; rg < 4; ++rg) {
      float v0 = fmaxf(qa[rg][0] + bqv, 0.0f);
      float v1 = fmaxf(qa[rg][1] + bqv, 0.0f);
      float v2 = fmaxf(qa[rg][2] + bqv, 0.0f);
      float v3 = fmaxf(qa[rg][3] + bqv, 0.0f);
      unsigned p01 = cvtpk(v0, v1), p23 = cvtpk(v2, v3);
      Qb[swz128(rg * 16 + lg * 4 + 0, col)] = (unsigned short)p01;
      Qb[swz128(rg * 16 + lg * 4 + 1, col)] = (unsigned short)(p01 >> 16);
      Qb[swz128(rg * 16 + lg * 4 + 2, col)] = (unsigned short)p23;
      Qb[swz128(rg * 16 + lg * 4 + 3, col)] = (unsigned short)(p23 >> 16);
    }
  }

  // ---------------- causal attention, head w (all strips wave-local) -------
  {
    const bf16x8 zf = (bf16x8){0, 0, 0, 0, 0, 0, 0, 0};
    bf16x8 kf[4], vf[2];
    #pragma unroll
    for (int pt = 0; pt < 4; ++pt)
      kf[pt] = (lg < 2) ? *(const bf16x8*)(Kb + swz128(pt * 16 + li, hc + lg * 8)) : zf;
    #pragma unroll
    for (int ks = 0; ks < 2; ++ks)
      vf[ks] = *(const bf16x8*)(Vt + swz64(hc + li, ks * 32 + lg * 8));

    #pragma unroll
    for (int qt = 0; qt < 4; ++qt) {
      bf16x8 qf = (lg < 2) ? *(const bf16x8*)(Qb + swz128(qt * 16 + li, hc + lg * 8)) : zf;
      f32x4 st[4];
      #pragma unroll
      for (int pt = 0; pt < 4; ++pt)
        if (pt <= qt)
          st[pt] = __builtin_amdgcn_mfma_f32_16x16x32_bf16(kf[pt], qf, (f32x4){0, 0, 0, 0}, 0, 0, 0);

      float ssum = 0.0f;
      unsigned pa[4], pb[4];
      #pragma unroll
      for (int pt = 0; pt < 4; ++pt) {
        if (pt > qt) { pa[pt] = 0; pb[pt] = 0; continue; }
        float e0 = exp2f(st[pt][0]);
        float e1 = exp2f(st[pt][1]);
        float e2 = exp2f(st[pt][2]);
        float e3 = exp2f(st[pt][3]);
        if (pt == qt) {  // diagonal tile: mask p_local > q_local
          e0 = (4 * lg + 0 > li) ? 0.0f : e0;
          e1 = (4 * lg + 1 > li) ? 0.0f : e1;
          e2 = (4 * lg + 2 > li) ? 0.0f : e2;
          e3 = (4 * lg + 3 > li) ? 0.0f : e3;
        }
        ssum += e0 + e1 + e2 + e3;
        pa[pt] = cvtpk(e0, e1);
        pb[pt] = cvtpk(e2, e3);
      }
      ssum += __shfl_xor(ssum, 16, 64);
      ssum += __shfl_xor(ssum, 32, 64);
      float rinv = 1.0f / ssum;

      f32x4 oa = (f32x4){0, 0, 0, 0};
      #pragma unroll
      for (int ks = 0; ks < 2; ++ks) {
        if (ks * 2 > qt) continue;
        unsigned x = pa[2 * ks], y = pa[2 * ks + 1];
        asm("v_permlane32_swap_b32 %0, %1" : "+v"(x), "+v"(y));
        asm("v_permlane16_swap_b32 %0, %1" : "+v"(x), "+v"(y));
        unsigned u2 = pb[2 * ks], v2 = pb[2 * ks + 1];
        asm("v_permlane32_swap_b32 %0, %1" : "+v"(u2), "+v"(v2));
        asm("v_permlane16_swap_b32 %0, %1" : "+v"(u2), "+v"(v2));
        union { unsigned uw[4]; bf16x8 h; } pu;
        pu.uw[0] = x; pu.uw[1] = u2; pu.uw[2] = y; pu.uw[3] = v2;
        oa = __builtin_amdgcn_mfma_f32_16x16x32_bf16(vf[ks], pu.h, oa, 0, 0, 0);
      }
      uint2 ov;
      ov.x = cvtpk(oa[0] * rinv, oa[1] * rinv);
      ov.y = cvtpk(oa[2] * rinv, oa[3] * rinv);
      *(uint2*)(AOb + swz128(qt * 16 + li, hc + lg * 4)) = ov;
    }
  }

  bar();  // B2: AO visible; Kb dead -> Br live (Vt still holds V? No: V was
          // only consumed via vf regs above, so Vt is dead too -> Cr at B3.)

  // ---- O1 col-strip: H1 -> Br ---------------------------------------------
  {
    f32x4 acc[4];
    #pragma unroll
    for (int i = 0; i < 4; ++i) acc[i] = (f32x4){0, 0, 0, 0};
    #pragma unroll
    for (int kk = 0; kk < 4; ++kk) {
      bf16x8 bc = *(const bf16x8*)(wo1t + (hc + li) * 128 + kk * 32 + lg * 8);
      #pragma unroll
      for (int rg = 0; rg < 4; ++rg) {
        bf16x8 af = *(const bf16x8*)(AOb + swz128(rg * 16 + li, kk * 32 + lg * 8));
        acc[rg] = __builtin_amdgcn_mfma_f32_16x16x32_bf16(af, bc, acc[rg], 0, 0, 0);
      }
    }
    float bvv = bo1[hc + li];
    int col = hc + li;
    #pragma unroll
    for (int rg = 0; rg < 4; ++rg) {
      unsigned p01 = cvtpk(fmaxf(acc[rg][0] + bvv, 0.0f), fmaxf(acc[rg][1] + bvv, 0.0f));
      unsigned p23 = cvtpk(fmaxf(acc[rg][2] + bvv, 0.0f), fmaxf(acc[rg][3] + bvv, 0.0f));
      Br[swz128(rg * 16 + lg * 4 + 0, col)] = (unsigned short)p01;
      Br[swz128(rg * 16 + lg * 4 + 1, col)] = (unsigned short)(p01 >> 16);
      Br[swz128(rg * 16 + lg * 4 + 2, col)] = (unsigned short)p23;
      Br[swz128(rg * 16 + lg * 4 + 3, col)] = (unsigned short)(p23 >> 16);
    }
  }
  bar();  // B3: H1 visible; Vt dead -> Cr live

  // ---- O2 col-strip + residual: x2 -> Cr ----------------------------------
  {
    f32x4 acc[4];
    #pragma unroll
    for (int i = 0; i < 4; ++i) acc[i] = (f32x4){0, 0, 0, 0};
    #pragma unroll
    for (int kk = 0; kk < 4; ++kk) {
      bf16x8 bc = *(const bf16x8*)(wo2t + (hc + li) * 128 + kk * 32 + lg * 8);
      #pragma unroll
      for (int rg = 0; rg < 4; ++rg) {
        bf16x8 af = *(const bf16x8*)(Br + swz128(rg * 16 + li, kk * 32 + lg * 8));
        acc[rg] = __builtin_amdgcn_mfma_f32_16x16x32_bf16(af, bc, acc[rg], 0, 0, 0);
      }
    }
    float bvv = bo2[hc + li];
    int col = hc + li;
    #pragma unroll
    for (int rg = 0; rg < 4; ++rg) {
      float x0 = xbase[(rg * 16 + lg * 4 + 0) * rs + col];
      float x1 = xbase[(rg * 16 + lg * 4 + 1) * rs + col];
      float x2v = xbase[(rg * 16 + lg * 4 + 2) * rs + col];
      float x3 = xbase[(rg * 16 + lg * 4 + 3) * rs + col];
      unsigned p01 = cvtpk(acc[rg][0] + bvv + x0, acc[rg][1] + bvv + x1);
      unsigned p23 = cvtpk(acc[rg][2] + bvv + x2v, acc[rg][3] + bvv + x3);
      Cr[swz128(rg * 16 + lg * 4 + 0, col)] = (unsigned short)p01;
      Cr[swz128(rg * 16 + lg * 4 + 1, col)] = (unsigned short)(p01 >> 16);
      Cr[swz128(rg * 16 + lg * 4 + 2, col)] = (unsigned short)p23;
      Cr[swz128(rg * 16 + lg * 4 + 3, col)] = (unsigned short)(p23 >> 16);
    }
  }
  bar();  // B4: x2 visible; Qb/AOb dead -> Ar (Xn2) live

  // ---- LN2 (wave w re-reads rows w*8..w*8+7 full-width) -> Xn2 in Ar ------
  {
    float4 gA = *(const float4*)(g2 + li * 8);
    float4 gB = *(const float4*)(g2 + li * 8 + 4);
    float4 bA = *(const float4*)(b2 + li * 8);
    float4 bB = *(const float4*)(b2 + li * 8 + 4);
    #pragma unroll
    for (int p = 0; p < 2; ++p) {
      int t = w * 8 + p * 4 + lg;
      uint4 v = *(const uint4*)(Cr + swz128(t, li * 8));
      float f0 = bf2f((unsigned short)v.x),  f1 = bf2f((unsigned short)(v.x >> 16));
      float f2v = bf2f((unsigned short)v.y), f3 = bf2f((unsigned short)(v.y >> 16));
      float f4 = bf2f((unsigned short)v.z),  f5 = bf2f((unsigned short)(v.z >> 16));
      float f6 = bf2f((unsigned short)v.w),  f7 = bf2f((unsigned short)(v.w >> 16));
      float s1 = f0 + f1 + f2v + f3 + f4 + f5 + f6 + f7;
      float s2 = f0 * f0 + f1 * f1 + f2v * f2v + f3 * f3 + f4 * f4 + f5 * f5 + f6 * f6 + f7 * f7;
      s1 = red16(s1); s2 = red16(s2);
      float mean = s1 * (1.0f / 128.0f);
      float var = fmaxf((s2 - s1 * mean) * (1.0f / 127.0f), 0.0f);  // ddof=1
      float iv = 1.0f / (sqrtf(var) + 1e-6f);
      unsigned o01 = cvtpk(gA.x * (f0 - mean) * iv + bA.x, gA.y * (f1 - mean) * iv + bA.y);
      unsigned o23 = cvtpk(gA.z * (f2v - mean) * iv + bA.z, gA.w * (f3 - mean) * iv + bA.w);
      unsigned o45 = cvtpk(gB.x * (f4 - mean) * iv + bB.x, gB.y * (f5 - mean) * iv + bB.y);
      unsigned o67 = cvtpk(gB.z * (f6 - mean) * iv + bB.z, gB.w * (f7 - mean) * iv + bB.w);
      *(uint4*)(Ar + swz128(t, li * 8)) = (uint4){o01, o23, o45, o67};  // Xn2
    }
  }
  bar();  // B5: Xn2 visible

  // ---- F1 col-strip: Hf -> Br ---------------------------------------------
  {
    f32x4 acc[4];
    #pragma unroll
    for (int i = 0; i < 4; ++i) acc[i] = (f32x4){0, 0, 0, 0};
    #pragma unroll
    for (int kk = 0; kk < 4; ++kk) {
      bf16x8 bc = *(const bf16x8*)(wf1t + (hc + li) * 128 + kk * 32 + lg * 8);
      #pragma unroll
      for (int rg = 0; rg < 4; ++rg) {
        bf16x8 af = *(const bf16x8*)(Ar + swz128(rg * 16 + li, kk * 32 + lg * 8));
        acc[rg] = __builtin_amdgcn_mfma_f32_16x16x32_bf16(af, bc, acc[rg], 0, 0, 0);
      }
    }
    float bvv = bf1[hc + li];
    int col = hc + li;
    #pragma unroll
    for (int rg = 0; rg < 4; ++rg) {
      unsigned p01 = cvtpk(fmaxf(acc[rg][0] + bvv, 0.0f), fmaxf(acc[rg][1] + bvv, 0.0f));
      unsigned p23 = cvtpk(fmaxf(acc[rg][2] + bvv, 0.0f), fmaxf(acc[rg][3] + bvv, 0.0f));
      Br[swz128(rg * 16 + lg * 4 + 0, col)] = (unsigned short)p01;
      Br[swz128(rg * 16 + lg * 4 + 1, col)] = (unsigned short)(p01 >> 16);
      Br[swz128(rg * 16 + lg * 4 + 2, col)] = (unsigned short)p23;
      Br[swz128(rg * 16 + lg * 4 + 3, col)] = (unsigned short)(p23 >> 16);
    }
  }
  bar();  // B6: Hf visible

  // ---- F2 col-strip + final residual (x2 from Cr) -> out ------------------
  {
    f32x4 acc[4];
    #pragma unroll
    for (int i = 0; i < 4; ++i) acc[i] = (f32x4){0, 0, 0, 0};
    #pragma unroll
    for (int kk = 0; kk < 4; ++kk) {
      bf16x8 bc = *(const bf16x8*)(wf2t + (hc + li) * 128 + kk * 32 + lg * 8);
      #pragma unroll
      for (int rg = 0; rg < 4; ++rg) {
        bf16x8 af = *(const bf16x8*)(Br + swz128(rg * 16 + li, kk * 32 + lg * 8));
        acc[rg] = __builtin_amdgcn_mfma_f32_16x16x32_bf16(af, bc, acc[rg], 0, 0, 0);
      }
    }
    float* obase = out + (b * TT * NN + n) * DD;
    float bvv = bf2[hc + li];
    int col = hc + li;
    #pragma unroll
    for (int rg = 0; rg < 4; ++rg) {
      #pragma unroll
      for (int r = 0; r < 4; ++r) {
        int row = rg * 16 + lg * 4 + r;
        float x2v = bf2f(Cr[swz128(row, col)]);
        obase[row * rs + col] = x2v + fmaxf(acc[rg][r] + bvv, 0.0f);
      }
    }
  }
  #undef SWZ256
}

extern "C" void kernel_launch(void* const* d_in, const int* in_sizes, int n_in,
                              void* d_out, int out_size, void* d_ws, size_t ws_size,
                              hipStream_t stream) {
  const float* x   = (const float*)d_in[0];
  const float* ste = (const float*)d_in[1];
  const float* g1 = (const float*)d_in[3];
  const float* b1 = (const float*)d_in[4];
  const float* g2 = (const float*)d_in[5];
  const float* b2 = (const float*)d_in[6];
  const float* Wq = (const float*)d_in[7];   const float* bq  = (const float*)d_in[8];
  const float* Wk = (const float*)d_in[9];   const float* bk  = (const float*)d_in[10];
  const float* Wv = (const float*)d_in[11];  const float* bv  = (const float*)d_in[12];
  const float* Wo1 = (const float*)d_in[13]; const float* bo1 = (const float*)d_in[14];
  const float* Wo2 = (const float*)d_in[15]; const float* bo2 = (const float*)d_in[16];
  const float* Wf1 = (const float*)d_in[17]; const float* bf1 = (const float*)d_in[18];
  const float* Wf2 = (const float*)d_in[19]; const float* bf2 = (const float*)d_in[20];
  float* out = (float*)d_out;

  unsigned short* wsu = (unsigned short*)d_ws;
  unsigned short* wq_t  = wsu;             // [128][256]
  unsigned short* wk_t  = wsu + 32768;
  unsigned short* wv_t  = wsu + 65536;
  unsigned short* wo1_t = wsu + 98304;     // [128][128]
  unsigned short* wo2_t = wsu + 114688;
  unsigned short* wf1_t = wsu + 131072;
  unsigned short* wf2_t = wsu + 147456;

  hipLaunchKernelGGL(wprep, dim3(128), dim3(256), 0, stream, Wq, wq_t, 256, 128);
  hipLaunchKernelGGL(wprep, dim3(128), dim3(256), 0, stream, Wk, wk_t, 256, 128);
  hipLaunchKernelGGL(wprep, dim3(128), dim3(256), 0, stream, Wv, wv_t, 256, 128);
  hipLaunchKernelGGL(wprep, dim3(64), dim3(256), 0, stream, Wo1, wo1_t, 128, 128);
  hipLaunchKernelGGL(wprep, dim3(64), dim3(256), 0, stream, Wo2, wo2_t, 128, 128);
  hipLaunchKernelGGL(wprep, dim3(64), dim3(256), 0, stream, Wf1, wf1_t, 128, 128);
  hipLaunchKernelGGL(wprep, dim3(64), dim3(256), 0, stream, Wf2, wf2_t, 128, 128);

  hipLaunchKernelGGL(fused_layer, dim3(8 * NN), dim3(512), 0, stream,
                     x, ste, g1, b1, g2, b2,
                     wq_t, bq, wk_t, bk, wv_t, bv,
                     wo1_t, bo1, wo2_t, bo2,
                     wf1_t, bf1, wf2_t, bf2, out);
}